// Round 1
// baseline (506.337 us; speedup 1.0000x reference)
//
#include <hip/hip_runtime.h>

typedef __attribute__((ext_vector_type(8))) short s16x8;
typedef __attribute__((ext_vector_type(4))) short s16x4;
typedef __attribute__((ext_vector_type(4))) float f32x4;

#define DEVINL __device__ __forceinline__

// ---------- bf16 helpers (manual RNE) ----------
DEVINL float b2f(short u){ return __uint_as_float(((unsigned)(unsigned short)u) << 16); }
DEVINL short f2bf(float f){
  unsigned u = __float_as_uint(f);
  u += 0x7fffu + ((u >> 16) & 1u);
  return (short)(u >> 16);
}

// ---------- MFMA wrappers ----------
DEVINL f32x4 mfma32(s16x8 a, s16x8 b, f32x4 c){
  // A: m=lane&15, k=8*(lane>>4)+i ; B: n=lane&15, k=8*(lane>>4)+i
  // D: n=lane&15, m=4*(lane>>4)+i   [guide §3, m89-verified]
  return __builtin_amdgcn_mfma_f32_16x16x32_bf16(a, b, c, 0, 0, 0);
}
DEVINL f32x4 mfma16(s16x4 a, s16x4 b, f32x4 c){
  // A/B: k=4*(lane>>4)+i, m/n=lane&15 ; D same as above (CDNA 16x16x16 layout)
#if __has_builtin(__builtin_amdgcn_mfma_f32_16x16x16bf16_1k)
  return __builtin_amdgcn_mfma_f32_16x16x16bf16_1k(a, b, c, 0, 0, 0);
#else
  f32x4 d;
  asm volatile("v_mfma_f32_16x16x16_bf16 %0, %1, %2, %3"
               : "=&v"(d) : "v"(a), "v"(b), "v"(c));
  return d;
#endif
}

// ---------- problem constants ----------
static const int Bc   = 4;
static const int Nc   = 2048;
static const int DIM  = 1024;
static const int Hc   = 16;
static const int HD   = 64;
static const int Tc   = Bc * Nc;      // 8192 tokens
static const int MLP  = 4096;
static const int D3   = 3072;

// ---------- ws layout (bytes) ----------
static const size_t OFF_XB    = 0;                         // 8192x1024 bf16
static const size_t OFF_WQKVT = OFF_XB    + 16777216;      // 3072x1024 bf16
static const size_t OFF_W1T   = OFF_WQKVT + 6291456;       // 4096x1024 bf16
static const size_t OFF_W2T   = OFF_W1T   + 8388608;       // 1024x4096 bf16
static const size_t OFF_WOUTT = OFF_W2T   + 8388608;       // 1024x1024 bf16
static const size_t OFF_QKV   = OFF_WOUTT + 2097152;       // 8192x3072 bf16
static const size_t OFF_QLN   = OFF_QKV   + 50331648;      // [64bh][2048][64] bf16
static const size_t OFF_KLN   = OFF_QLN   + 16777216;
static const size_t OFF_VT    = OFF_KLN   + 16777216;      // [64bh][64d][2048] bf16
static const size_t OFF_ATTNV = OFF_VT    + 16777216;      // 8192x1024 bf16
// aliases of dead regions:
static const size_t OFF_H     = OFF_QKV;                   // 8192x4096 bf16 (over qkv+qln)
static const size_t OFF_P2    = OFF_KLN;                   // 8192x1024 bf16
static const size_t OFF_A2    = OFF_VT;                    // 8192x1024 bf16
// total required: OFF_ATTNV + 16777216 = 159,383,552 B (~152 MB)

// ============================================================
// x fp32 -> bf16 (8 elems / thread)
// ============================================================
__global__ __launch_bounds__(256) void conv_x(const float* __restrict__ x, short* __restrict__ xb){
  size_t i = ((size_t)blockIdx.x * 256 + threadIdx.x) * 8;
  f32x4 v0 = *(const f32x4*)(x + i);
  f32x4 v1 = *(const f32x4*)(x + i + 4);
  s16x8 o;
#pragma unroll
  for (int j = 0; j < 4; ++j){ o[j] = f2bf(v0[j]); o[4+j] = f2bf(v1[j]); }
  *(s16x8*)(xb + i) = o;
}

// ============================================================
// W[K][N] fp32 -> Wt[N][K] bf16 (32x32 LDS tiles)
// ============================================================
__global__ __launch_bounds__(256) void transpose_conv(const float* __restrict__ W, short* __restrict__ Wt,
                                                      int K, int N){
  __shared__ float tile[32][33];
  int ntx = N >> 5;
  int tx = blockIdx.x % ntx, ty = blockIdx.x / ntx;
  int r = threadIdx.x >> 3, c = (threadIdx.x & 7) * 4;
  f32x4 v = *(const f32x4*)(W + (size_t)(ty*32 + r)*N + tx*32 + c);
  tile[r][c] = v[0]; tile[r][c+1] = v[1]; tile[r][c+2] = v[2]; tile[r][c+3] = v[3];
  __syncthreads();
  s16x4 o;
#pragma unroll
  for (int j = 0; j < 4; ++j) o[j] = f2bf(tile[c+j][r]);
  *(s16x4*)(Wt + (size_t)(tx*32 + r)*K + ty*32 + c) = o;
}

// ============================================================
// GEMM: C[M][N] = act(A[M][K] @ Bt[N][K]^T + bias), all bf16, acc fp32
// 128x128 tile, BK=64, 256 thr (4 waves 2x2), 16x16x32 MFMA
// ============================================================
__global__ __launch_bounds__(256) void gemm_bf16(const short* __restrict__ A, const short* __restrict__ Bt,
                                                 short* __restrict__ C, const float* __restrict__ bias,
                                                 int M, int N, int K, int act){
  __shared__ short As[128*72];   // +8 pad: stride 144B -> conflict-free b128 reads
  __shared__ short Bs[128*72];
  int tid = threadIdx.x;
  int wave = tid >> 6, lane = tid & 63;
  int wm = wave >> 1, wn = wave & 1;
  int lr = lane & 15, g = lane >> 4;
  int nT = N >> 7;
  int bm = blockIdx.x / nT, bn = blockIdx.x % nT;

  int sr = tid >> 2;            // staging row 0..63 (and +64)
  int cs = (tid & 3) * 16;      // staging col 0,16,32,48

  const short* aptr = A + (size_t)(bm*128 + sr)*K + cs;
  const short* bptr = Bt + (size_t)(bn*128 + sr)*K + cs;

  f32x4 acc[4][4] = {};

  for (int k0 = 0; k0 < K; k0 += 64){
#pragma unroll
    for (int h2 = 0; h2 < 2; ++h2){
      const short* ap = aptr + (size_t)h2*64*K;
      const short* bp = bptr + (size_t)h2*64*K;
      int rr = sr + h2*64;
      *(s16x8*)&As[rr*72 + cs]     = *(const s16x8*)ap;
      *(s16x8*)&As[rr*72 + cs + 8] = *(const s16x8*)(ap + 8);
      *(s16x8*)&Bs[rr*72 + cs]     = *(const s16x8*)bp;
      *(s16x8*)&Bs[rr*72 + cs + 8] = *(const s16x8*)(bp + 8);
    }
    aptr += 64; bptr += 64;
    __syncthreads();
#pragma unroll
    for (int kk = 0; kk < 2; ++kk){
      s16x8 af[4], bfr[4];
#pragma unroll
      for (int mi = 0; mi < 4; ++mi)
        af[mi] = *(const s16x8*)&As[(wm*64 + mi*16 + lr)*72 + kk*32 + g*8];
#pragma unroll
      for (int ni = 0; ni < 4; ++ni)
        bfr[ni] = *(const s16x8*)&Bs[(wn*64 + ni*16 + lr)*72 + kk*32 + g*8];
#pragma unroll
      for (int mi = 0; mi < 4; ++mi)
#pragma unroll
        for (int ni = 0; ni < 4; ++ni)
          acc[mi][ni] = mfma32(af[mi], bfr[ni], acc[mi][ni]);
    }
    __syncthreads();
  }

#pragma unroll
  for (int ni = 0; ni < 4; ++ni){
    int col = bn*128 + wn*64 + ni*16 + lr;
    float bv = bias ? bias[col] : 0.f;
#pragma unroll
    for (int mi = 0; mi < 4; ++mi){
      int row0 = bm*128 + wm*64 + mi*16 + 4*g;
      f32x4 v = acc[mi][ni];
#pragma unroll
      for (int i = 0; i < 4; ++i){
        float val = v[i] + bv;
        if (act == 1) val = 0.5f * val * (1.f + erff(val * 0.70710678118f));
        C[(size_t)(row0 + i)*N + col] = f2bf(val);
      }
    }
  }
}

// ============================================================
// q/k LayerNorm (over d=64) + reorg to [bh][n][d]; v -> Vt [bh][d][n]
// block: (bh, 64-token chunk); 4 threads per token
// ============================================================
__global__ __launch_bounds__(256) void ln_reorg(const short* __restrict__ qkv, short* __restrict__ qln,
                                                short* __restrict__ kln, short* __restrict__ vtb){
  __shared__ short vtile[64*72];
  int bh = blockIdx.x >> 5, tch = blockIdx.x & 31;
  int b = bh >> 4, h = bh & 15;
  int tq = threadIdx.x >> 2, j = threadIdx.x & 3;
  size_t row = (size_t)b*Nc + tch*64 + tq;
  const short* base = qkv + row*D3 + h*64 + j*16;
  size_t orow = ((size_t)bh*Nc + tch*64 + tq)*64 + j*16;

#pragma unroll
  for (int part = 0; part < 2; ++part){   // 0 = q (scale 1/32), 1 = k
    const short* src = base + part*DIM;
    s16x8 u0 = *(const s16x8*)src;
    s16x8 u1 = *(const s16x8*)(src + 8);
    float f[16]; float s = 0.f, sq = 0.f;
#pragma unroll
    for (int i = 0; i < 8; ++i){ f[i] = b2f(u0[i]); f[8+i] = b2f(u1[i]); }
#pragma unroll
    for (int i = 0; i < 16; ++i){ s += f[i]; sq += f[i]*f[i]; }
    s  += __shfl_xor(s, 1);  s  += __shfl_xor(s, 2);
    sq += __shfl_xor(sq, 1); sq += __shfl_xor(sq, 2);
    float mu = s * (1.f/64.f);
    float var = sq * (1.f/64.f) - mu*mu;
    float inv = rsqrtf(var + 1e-5f) * (part == 0 ? 0.03125f : 1.f); // fold dot-scale into q
    s16x8 o0, o1;
#pragma unroll
    for (int i = 0; i < 8; ++i){ o0[i] = f2bf((f[i]-mu)*inv); o1[i] = f2bf((f[8+i]-mu)*inv); }
    short* dst = (part == 0 ? qln : kln) + orow;
    *(s16x8*)dst = o0; *(s16x8*)(dst + 8) = o1;
  }

  // v: stage [token][d] then write transposed [d][token]
  s16x8 v0 = *(const s16x8*)(base + 2*DIM);
  s16x8 v1 = *(const s16x8*)(base + 2*DIM + 8);
  *(s16x8*)&vtile[tq*72 + j*16]     = v0;
  *(s16x8*)&vtile[tq*72 + j*16 + 8] = v1;
  __syncthreads();
  s16x8 o0, o1;
#pragma unroll
  for (int i = 0; i < 8; ++i){
    o0[i] = vtile[(j*16 + i)*72 + tq];
    o1[i] = vtile[(j*16 + 8 + i)*72 + tq];
  }
  short* vdst = vtb + ((size_t)bh*64 + tq)*Nc + tch*64 + j*16;
  *(s16x8*)vdst = o0; *(s16x8*)(vdst + 8) = o1;
}

// ============================================================
// Flash attention, swapped-QK^T form. Block = (bh, 64 q rows), 4 waves x 16q.
// S^T = mfma32(K, Q); per-lane q = lane&15; PV via 16x16x16 (B-frag == S^T D-layout).
// ============================================================
__global__ __launch_bounds__(256) void attn_kern(const short* __restrict__ qln, const short* __restrict__ kln,
                                                 const short* __restrict__ vtb, short* __restrict__ attnv){
  __shared__ short Ks[64*72];   // [key][d], +8 pad
  __shared__ short Vs[64*72];   // [d][key], +8 pad
  int bh = blockIdx.x >> 5, qt = blockIdx.x & 31;
  int b = bh >> 4, h = bh & 15;
  int w = threadIdx.x >> 6, lane = threadIdx.x & 63;
  int lr = lane & 15, g = lane >> 4;
  int qrow = qt*64 + w*16 + lr;

  const short* qp = qln + ((size_t)bh*Nc + qrow)*64 + g*8;
  s16x8 qf0 = *(const s16x8*)qp;          // d = 8g..8g+7
  s16x8 qf1 = *(const s16x8*)(qp + 32);   // d = 32+8g..

  f32x4 acc[4] = {};                      // acc[dvb]: O^T[dv=dvb*16+4g+i][q=lane&15]
  float mrun = -INFINITY, l = 0.f;

  int tr = threadIdx.x >> 2, seg = (threadIdx.x & 3) * 16;

  for (int kt = 0; kt < Nc; kt += 64){
    const short* ksrc = kln + ((size_t)bh*Nc + kt + tr)*64 + seg;
    *(s16x8*)&Ks[tr*72 + seg]     = *(const s16x8*)ksrc;
    *(s16x8*)&Ks[tr*72 + seg + 8] = *(const s16x8*)(ksrc + 8);
    const short* vsrc = vtb + ((size_t)bh*64 + tr)*Nc + kt + seg;
    *(s16x8*)&Vs[tr*72 + seg]     = *(const s16x8*)vsrc;
    *(s16x8*)&Vs[tr*72 + seg + 8] = *(const s16x8*)(vsrc + 8);
    __syncthreads();

#pragma unroll
    for (int kc = 0; kc < 4; ++kc){
      s16x8 kf0 = *(const s16x8*)&Ks[(kc*16 + lr)*72 + g*8];
      s16x8 kf1 = *(const s16x8*)&Ks[(kc*16 + lr)*72 + 32 + g*8];
      f32x4 st = {0.f, 0.f, 0.f, 0.f};
      st = mfma32(kf0, qf0, st);
      st = mfma32(kf1, qf1, st);   // S^T[key=kc*16+4g+i][q=lane&15], scale pre-folded

      float cmax = fmaxf(fmaxf(st[0], st[1]), fmaxf(st[2], st[3]));
      cmax = fmaxf(cmax, __shfl_xor(cmax, 16));
      cmax = fmaxf(cmax, __shfl_xor(cmax, 32));
      if (cmax > mrun + 8.f){               // defer-max (T13): rescale only on big jump
        float fr = __expf(mrun - cmax);
        l *= fr;
#pragma unroll
        for (int d2 = 0; d2 < 4; ++d2) acc[d2] *= fr;
        mrun = cmax;
      }
      float p0 = __expf(st[0] - mrun), p1 = __expf(st[1] - mrun);
      float p2 = __expf(st[2] - mrun), p3 = __expf(st[3] - mrun);
      l += p0 + p1 + p2 + p3;               // partial (this lane-group's 4 keys)
      s16x4 pf; pf[0] = f2bf(p0); pf[1] = f2bf(p1); pf[2] = f2bf(p2); pf[3] = f2bf(p3);
#pragma unroll
      for (int dvb = 0; dvb < 4; ++dvb){
        s16x4 vf = *(const s16x4*)&Vs[(dvb*16 + lr)*72 + kc*16 + g*4];
        acc[dvb] = mfma16(vf, pf, acc[dvb]);
      }
    }
    __syncthreads();
  }

  l += __shfl_xor(l, 16);
  l += __shfl_xor(l, 32);
  float inv = 1.f / l;
  short* orow = attnv + ((size_t)(b*Nc + qrow))*DIM + h*64;
#pragma unroll
  for (int dvb = 0; dvb < 4; ++dvb)
#pragma unroll
    for (int i = 0; i < 4; ++i)
      orow[dvb*16 + 4*g + i] = f2bf(acc[dvb][i] * inv);
}

// ============================================================
// out = LayerNorm(a2 + p2) over 1024, fp32 out. One block per row.
// ============================================================
__global__ __launch_bounds__(256) void final_ln(const short* __restrict__ a2, const short* __restrict__ p2,
                                                float* __restrict__ out){
  __shared__ float red[16];
  int row = blockIdx.x, tid = threadIdx.x;
  size_t base = (size_t)row*DIM + tid*4;
  s16x4 a = *(const s16x4*)(a2 + base);
  s16x4 p = *(const s16x4*)(p2 + base);
  float v[4]; float s = 0.f, sq = 0.f;
#pragma unroll
  for (int i = 0; i < 4; ++i){ v[i] = b2f(a[i]) + b2f(p[i]); s += v[i]; sq += v[i]*v[i]; }
#pragma unroll
  for (int m = 1; m < 64; m <<= 1){ s += __shfl_xor(s, m); sq += __shfl_xor(sq, m); }
  int wv = tid >> 6;
  if ((tid & 63) == 0){ red[wv] = s; red[8 + wv] = sq; }
  __syncthreads();
  if (tid == 0){
    float S = red[0] + red[1] + red[2] + red[3];
    float Q = red[8] + red[9] + red[10] + red[11];
    float mu = S * (1.f/1024.f);
    float var = Q * (1.f/1024.f) - mu*mu;
    red[12] = mu; red[13] = rsqrtf(var + 1e-5f);
  }
  __syncthreads();
  float mu = red[12], inv = red[13];
#pragma unroll
  for (int i = 0; i < 4; ++i) out[base + i] = (v[i] - mu) * inv;
}

// ============================================================
extern "C" void kernel_launch(void* const* d_in, const int* in_sizes, int n_in,
                              void* d_out, int out_size, void* d_ws, size_t ws_size,
                              hipStream_t stream){
  const float* x    = (const float*)d_in[0];
  const float* Wqkv = (const float*)d_in[1];
  const float* W1   = (const float*)d_in[2];
  const float* b1   = (const float*)d_in[3];
  const float* W2   = (const float*)d_in[4];
  const float* b2   = (const float*)d_in[5];
  const float* Wout = (const float*)d_in[6];
  const float* bout = (const float*)d_in[7];
  float* out = (float*)d_out;
  char* ws = (char*)d_ws;

  short* xb    = (short*)(ws + OFF_XB);
  short* wqkvt = (short*)(ws + OFF_WQKVT);
  short* w1t   = (short*)(ws + OFF_W1T);
  short* w2t   = (short*)(ws + OFF_W2T);
  short* woutt = (short*)(ws + OFF_WOUTT);
  short* qkv   = (short*)(ws + OFF_QKV);
  short* qln   = (short*)(ws + OFF_QLN);
  short* kln   = (short*)(ws + OFF_KLN);
  short* vtb   = (short*)(ws + OFF_VT);
  short* attnv = (short*)(ws + OFF_ATTNV);
  short* hbuf  = (short*)(ws + OFF_H);
  short* p2    = (short*)(ws + OFF_P2);
  short* a2    = (short*)(ws + OFF_A2);

  conv_x<<<4096, 256, 0, stream>>>(x, xb);
  transpose_conv<<<(DIM/32)*(D3/32),  256, 0, stream>>>(Wqkv, wqkvt, DIM, D3);
  transpose_conv<<<(DIM/32)*(MLP/32), 256, 0, stream>>>(W1, w1t, DIM, MLP);
  transpose_conv<<<(MLP/32)*(DIM/32), 256, 0, stream>>>(W2, w2t, MLP, DIM);
  transpose_conv<<<(DIM/32)*(DIM/32), 256, 0, stream>>>(Wout, woutt, DIM, DIM);

  gemm_bf16<<<(Tc/128)*(D3/128), 256, 0, stream>>>(xb, wqkvt, qkv, nullptr, Tc, D3, DIM, 0);
  ln_reorg<<<64*32, 256, 0, stream>>>(qkv, qln, kln, vtb);
  attn_kern<<<64*32, 256, 0, stream>>>(qln, kln, vtb, attnv);

  gemm_bf16<<<(Tc/128)*(MLP/128), 256, 0, stream>>>(xb, w1t, hbuf, b1, Tc, MLP, DIM, 1);
  gemm_bf16<<<(Tc/128)*(DIM/128), 256, 0, stream>>>(hbuf, w2t, p2, b2, Tc, DIM, MLP, 0);
  gemm_bf16<<<(Tc/128)*(DIM/128), 256, 0, stream>>>(attnv, woutt, a2, bout, Tc, DIM, DIM, 0);

  final_ln<<<Tc, 256, 0, stream>>>(a2, p2, out);
}

// Round 2
// 503.521 us; speedup vs baseline: 1.0056x; 1.0056x over previous
//
#include <hip/hip_runtime.h>

typedef __attribute__((ext_vector_type(8))) short s16x8;
typedef __attribute__((ext_vector_type(4))) short s16x4;
typedef __attribute__((ext_vector_type(4))) float f32x4;
typedef __attribute__((ext_vector_type(16))) float f32x16;
typedef __attribute__((ext_vector_type(2))) unsigned uint2v;

#define DEVINL __device__ __forceinline__

// ---------- bf16 helpers (manual RNE) ----------
DEVINL float b2f(short u){ return __uint_as_float(((unsigned)(unsigned short)u) << 16); }
DEVINL short f2bf(float f){
  unsigned u = __float_as_uint(f);
  u += 0x7fffu + ((u >> 16) & 1u);
  return (short)(u >> 16);
}
DEVINL unsigned pkbf(float a, float b){
  return (unsigned)(unsigned short)f2bf(a) | ((unsigned)(unsigned short)f2bf(b) << 16);
}

#if __has_builtin(__builtin_amdgcn_exp2f)
#define EXP2F __builtin_amdgcn_exp2f
#else
#define EXP2F exp2f
#endif

// ---------- MFMA wrappers ----------
DEVINL f32x4 mfma32(s16x8 a, s16x8 b, f32x4 c){
  // A: m=lane&15, k=8*(lane>>4)+i ; B: n=lane&15, k=8*(lane>>4)+i
  // D: n=lane&15, m=4*(lane>>4)+i   [guide §3, m89-verified; worked in R1]
  return __builtin_amdgcn_mfma_f32_16x16x32_bf16(a, b, c, 0, 0, 0);
}
DEVINL f32x16 mfma3216(s16x8 a, s16x8 b, f32x16 c){
  // A: m=lane&31, k=8*(lane>>5)+i ; B: n=lane&31, k=8*(lane>>5)+i
  // D: col=lane&31, row=(reg&3)+8*(reg>>2)+4*(lane>>5)  [m74/m101-verified]
  return __builtin_amdgcn_mfma_f32_32x32x16_bf16(a, b, c, 0, 0, 0);
}

// permlane32_swap: dst.hi <-> src.lo  =>  r[0]={dst.lo, src.lo}, r[1]={dst.hi, src.hi}
// (orientation per guide's verified T12 usage)
DEVINL uint2v pl32swap(unsigned a, unsigned b){
#if __has_builtin(__builtin_amdgcn_permlane32_swap)
  return __builtin_amdgcn_permlane32_swap(a, b, false, false);
#else
  asm volatile("v_permlane32_swap_b32 %0, %1" : "+v"(a), "+v"(b));
  uint2v r; r[0] = a; r[1] = b; return r;
#endif
}

// ---------- async global->LDS (width 16) ----------
typedef const unsigned __attribute__((address_space(1)))* gas1;
typedef unsigned __attribute__((address_space(3)))* las3;
DEVINL void gload16(const short* g, short* l){
  // LDS dest is wave-uniform base + lane*16B (m104/m108); global src per-lane.
  __builtin_amdgcn_global_load_lds((gas1)g, (las3)l, 16, 0, 0);
}

// ---------- problem constants ----------
static const int Bc   = 4;
static const int Nc   = 2048;
static const int DIM  = 1024;
static const int Tc   = Bc * Nc;      // 8192 tokens
static const int MLP  = 4096;
static const int D3   = 3072;

// ---------- ws layout (bytes) ----------
static const size_t OFF_XB    = 0;                         // 8192x1024 bf16
static const size_t OFF_WQKVT = OFF_XB    + 16777216;      // 3072x1024 bf16
static const size_t OFF_W1T   = OFF_WQKVT + 6291456;       // 4096x1024 bf16
static const size_t OFF_W2T   = OFF_W1T   + 8388608;       // 1024x4096 bf16
static const size_t OFF_WOUTT = OFF_W2T   + 8388608;       // 1024x1024 bf16
static const size_t OFF_QKV   = OFF_WOUTT + 2097152;       // 8192x3072 bf16
static const size_t OFF_QLN   = OFF_QKV   + 50331648;      // [64bh][2048][64] bf16
static const size_t OFF_KLN   = OFF_QLN   + 16777216;
static const size_t OFF_VT    = OFF_KLN   + 16777216;      // [64bh][64d][2048] bf16
static const size_t OFF_ATTNV = OFF_VT    + 16777216;      // 8192x1024 bf16
// aliases of dead regions (stream-ordered safe):
static const size_t OFF_H     = OFF_QKV;                   // 8192x4096 bf16 (over qkv+qln)
static const size_t OFF_P2    = OFF_KLN;
static const size_t OFF_A2    = OFF_VT;

// ============================================================
// x fp32 -> bf16
// ============================================================
__global__ __launch_bounds__(256) void conv_x(const float* __restrict__ x, short* __restrict__ xb){
  size_t i = ((size_t)blockIdx.x * 256 + threadIdx.x) * 8;
  f32x4 v0 = *(const f32x4*)(x + i);
  f32x4 v1 = *(const f32x4*)(x + i + 4);
  s16x8 o;
#pragma unroll
  for (int j = 0; j < 4; ++j){ o[j] = f2bf(v0[j]); o[4+j] = f2bf(v1[j]); }
  *(s16x8*)(xb + i) = o;
}

// ============================================================
// W[K][N] fp32 -> Wt[N][K] bf16
// ============================================================
__global__ __launch_bounds__(256) void transpose_conv(const float* __restrict__ W, short* __restrict__ Wt,
                                                      int K, int N){
  __shared__ float tile[32][33];
  int ntx = N >> 5;
  int tx = blockIdx.x % ntx, ty = blockIdx.x / ntx;
  int r = threadIdx.x >> 3, c = (threadIdx.x & 7) * 4;
  f32x4 v = *(const f32x4*)(W + (size_t)(ty*32 + r)*N + tx*32 + c);
  tile[r][c] = v[0]; tile[r][c+1] = v[1]; tile[r][c+2] = v[2]; tile[r][c+3] = v[3];
  __syncthreads();
  s16x4 o;
#pragma unroll
  for (int j = 0; j < 4; ++j) o[j] = f2bf(tile[c+j][r]);
  *(s16x4*)(Wt + (size_t)(tx*32 + r)*K + ty*32 + c) = o;
}

// ============================================================
// GEMM (m97 structure): 128x128 tile, BK=64, linear LDS, global_load_lds x16B
// ============================================================
__global__ __launch_bounds__(256) void gemm_bf16(const short* __restrict__ A, const short* __restrict__ Bt,
                                                 short* __restrict__ C, const float* __restrict__ bias,
                                                 int M, int N, int K, int act){
  __shared__ short As[128*64];   // linear [row][64] — required by global_load_lds
  __shared__ short Bs[128*64];
  int tid = threadIdx.x;
  int wave = tid >> 6, lane = tid & 63;
  int wm = wave >> 1, wn = wave & 1;
  int lr = lane & 15, g = lane >> 4;
  int nT = N >> 7;
  int bm = blockIdx.x / nT, bn = blockIdx.x % nT;

  // staging: pass p covers rows p*32 + wave*8 + lane/8, cols (lane&7)*8 (16B)
  int srow = wave*8 + (lane >> 3);
  int scol = (lane & 7) * 8;
  const short* ag = A  + (size_t)(bm*128 + srow)*K + scol;
  const short* bg = Bt + (size_t)(bn*128 + srow)*K + scol;
  short* al = &As[wave*512];   // wave-uniform; HW adds lane*16B
  short* bl = &Bs[wave*512];

  f32x4 acc[4][4] = {};

  for (int k0 = 0; k0 < K; k0 += 64){
#pragma unroll
    for (int p = 0; p < 4; ++p){
      gload16(ag + (size_t)p*32*K, al + p*2048);
      gload16(bg + (size_t)p*32*K, bl + p*2048);
    }
    ag += 64; bg += 64;
    __syncthreads();   // compiler drains vmcnt(0) before s_barrier (m97 behavior)
#pragma unroll
    for (int kk = 0; kk < 2; ++kk){
      s16x8 af[4], bfr[4];
#pragma unroll
      for (int mi = 0; mi < 4; ++mi)
        af[mi] = *(const s16x8*)&As[(wm*64 + mi*16 + lr)*64 + kk*32 + g*8];
#pragma unroll
      for (int ni = 0; ni < 4; ++ni)
        bfr[ni] = *(const s16x8*)&Bs[(wn*64 + ni*16 + lr)*64 + kk*32 + g*8];
#pragma unroll
      for (int mi = 0; mi < 4; ++mi)
#pragma unroll
        for (int ni = 0; ni < 4; ++ni)
          acc[mi][ni] = mfma32(af[mi], bfr[ni], acc[mi][ni]);
    }
    __syncthreads();
  }

#pragma unroll
  for (int ni = 0; ni < 4; ++ni){
    int col = bn*128 + wn*64 + ni*16 + lr;
    float bv = bias ? bias[col] : 0.f;
#pragma unroll
    for (int mi = 0; mi < 4; ++mi){
      int row0 = bm*128 + wm*64 + mi*16 + 4*g;
      f32x4 v = acc[mi][ni];
#pragma unroll
      for (int i = 0; i < 4; ++i){
        float val = v[i] + bv;
        if (act == 1) val = 0.5f * val * (1.f + erff(val * 0.70710678118f));
        C[(size_t)(row0 + i)*N + col] = f2bf(val);
      }
    }
  }
}

// ============================================================
// q/k LayerNorm (d=64) + head-reorg; v -> Vt [bh][d][n]
// q additionally scaled by dim^-0.5 * log2(e)  (exp2-domain softmax)
// ============================================================
__global__ __launch_bounds__(256) void ln_reorg(const short* __restrict__ qkv, short* __restrict__ qln,
                                                short* __restrict__ kln, short* __restrict__ vtb){
  __shared__ short vtile[64*72];
  int bh = blockIdx.x >> 5, tch = blockIdx.x & 31;
  int b = bh >> 4, h = bh & 15;
  int tq = threadIdx.x >> 2, j = threadIdx.x & 3;
  size_t row = (size_t)b*Nc + tch*64 + tq;
  const short* base = qkv + row*D3 + h*64 + j*16;
  size_t orow = ((size_t)bh*Nc + tch*64 + tq)*64 + j*16;

#pragma unroll
  for (int part = 0; part < 2; ++part){
    const short* src = base + part*DIM;
    s16x8 u0 = *(const s16x8*)src;
    s16x8 u1 = *(const s16x8*)(src + 8);
    float f[16]; float s = 0.f, sq = 0.f;
#pragma unroll
    for (int i = 0; i < 8; ++i){ f[i] = b2f(u0[i]); f[8+i] = b2f(u1[i]); }
#pragma unroll
    for (int i = 0; i < 16; ++i){ s += f[i]; sq += f[i]*f[i]; }
    s  += __shfl_xor(s, 1);  s  += __shfl_xor(s, 2);
    sq += __shfl_xor(sq, 1); sq += __shfl_xor(sq, 2);
    float mu = s * (1.f/64.f);
    float var = sq * (1.f/64.f) - mu*mu;
    // 0.03125 (dim^-0.5) * 1.4426950408889634 (log2 e) folded into q
    float inv = rsqrtf(var + 1e-5f) * (part == 0 ? 0.04508422003f : 1.f);
    s16x8 o0, o1;
#pragma unroll
    for (int i = 0; i < 8; ++i){ o0[i] = f2bf((f[i]-mu)*inv); o1[i] = f2bf((f[8+i]-mu)*inv); }
    short* dst = (part == 0 ? qln : kln) + orow;
    *(s16x8*)dst = o0; *(s16x8*)(dst + 8) = o1;
  }

  s16x8 v0 = *(const s16x8*)(base + 2*DIM);
  s16x8 v1 = *(const s16x8*)(base + 2*DIM + 8);
  *(s16x8*)&vtile[tq*72 + j*16]     = v0;
  *(s16x8*)&vtile[tq*72 + j*16 + 8] = v1;
  __syncthreads();
  s16x8 o0, o1;
#pragma unroll
  for (int i = 0; i < 8; ++i){
    o0[i] = vtile[(j*16 + i)*72 + tq];
    o1[i] = vtile[(j*16 + 8 + i)*72 + tq];
  }
  short* vdst = vtb + ((size_t)bh*64 + tq)*Nc + tch*64 + j*16;
  *(s16x8*)vdst = o0; *(s16x8*)(vdst + 8) = o1;
}

// ============================================================
// Flash attention, 32x32 swapped form. Block = (bh, 128 q rows), 4 waves x 32 q.
// S^T = mfma_32x32x16(K, Q) — lane owns q=lane&31, 16 keys (of 32) in regs.
// Softmax in exp2 domain; P^T B-frag built via cvt-pack + permlane32_swap (T12).
// PV = mfma_32x32x16(V^T, P^T), zero shuffles.
// ============================================================
__global__ __launch_bounds__(256) void attn_kern(const short* __restrict__ qln, const short* __restrict__ kln,
                                                 const short* __restrict__ vtb, short* __restrict__ attnv){
  __shared__ short Ks[64*72];   // [key][d], pad 72 (row stride 144B -> 2-way max)
  __shared__ short Vs[64*72];   // [dv][key], pad 72
  int bh = blockIdx.x >> 4, qt = blockIdx.x & 15;
  int b = bh >> 4, h = bh & 15;
  int w = threadIdx.x >> 6, lane = threadIdx.x & 63;
  int lq = lane & 31, hi = lane >> 5;
  int qrow = qt*128 + w*32 + lq;

  // Q B-frags: mfma m needs Q[q=lq][d = m*16 + hi*8 + i]
  const short* qp = qln + ((size_t)bh*Nc + qrow)*64 + hi*8;
  s16x8 qf[4];
#pragma unroll
  for (int m = 0; m < 4; ++m) qf[m] = *(const s16x8*)(qp + m*16);

  f32x16 o0 = {0,0,0,0,0,0,0,0,0,0,0,0,0,0,0,0};  // O^T[dv=0..31][q=lq]
  f32x16 o1 = {0,0,0,0,0,0,0,0,0,0,0,0,0,0,0,0};  // O^T[dv=32..63][q=lq]
  float mrun = -INFINITY, l = 0.f;

  int tr = threadIdx.x >> 2, seg = (threadIdx.x & 3) * 16;
  const short* kbase = kln + ((size_t)bh*Nc + tr)*64 + seg;
  const short* vbase = vtb + ((size_t)bh*64 + tr)*Nc + seg;
  short* ksd = &Ks[tr*72 + seg];
  short* vsd = &Vs[tr*72 + seg];

  for (int kt = 0; kt < Nc; kt += 64){
    const short* ksrc = kbase + (size_t)kt*64;
    *(s16x8*)ksd       = *(const s16x8*)ksrc;
    *(s16x8*)(ksd + 8) = *(const s16x8*)(ksrc + 8);
    const short* vsrc = vbase + kt;
    *(s16x8*)vsd       = *(const s16x8*)vsrc;
    *(s16x8*)(vsd + 8) = *(const s16x8*)(vsrc + 8);
    __syncthreads();

#pragma unroll
    for (int kc = 0; kc < 2; ++kc){
      // S^T over 32 keys: key = kc*32 + (r&3)+8*(r>>2)+4*hi, q = lq
      f32x16 st = {0,0,0,0,0,0,0,0,0,0,0,0,0,0,0,0};
#pragma unroll
      for (int m = 0; m < 4; ++m){
        s16x8 kf = *(const s16x8*)&Ks[(kc*32 + lq)*72 + m*16 + hi*8];
        st = mfma3216(kf, qf[m], st);
      }
      float cmax = st[0];
#pragma unroll
      for (int r = 1; r < 16; ++r) cmax = fmaxf(cmax, st[r]);
      cmax = fmaxf(cmax, __shfl_xor(cmax, 32));
      if (__any(cmax > mrun + 8.f)){           // defer-max, wave-uniform gate (T13)
        float mnew = fmaxf(mrun, cmax);
        float fr = EXP2F(mrun - mnew);
        l *= fr;
#pragma unroll
        for (int r = 0; r < 16; ++r){ o0[r] *= fr; o1[r] *= fr; }
        mrun = mnew;
      }
      float p[16];
#pragma unroll
      for (int r = 0; r < 16; ++r){ p[r] = EXP2F(st[r] - mrun); l += p[r]; }

      // Build P^T B-frags (keys kh*16..kh*16+15) via pack + permlane32_swap:
      // swap(pk(p0,p1), pk(p4,p5)) -> {word0, word2}; swap(pk(p2,p3), pk(p6,p7)) -> {word1, word3}
#pragma unroll
      for (int kh = 0; kh < 2; ++kh){
        int r0 = kh*8;
        unsigned wa = pkbf(p[r0+0], p[r0+1]);
        unsigned wb = pkbf(p[r0+4], p[r0+5]);
        unsigned wc = pkbf(p[r0+2], p[r0+3]);
        unsigned wd = pkbf(p[r0+6], p[r0+7]);
        uint2v s1 = pl32swap(wa, wb);
        uint2v s2 = pl32swap(wc, wd);
        union { unsigned u[4]; s16x8 v; } pu;
        pu.u[0] = s1[0]; pu.u[1] = s2[0]; pu.u[2] = s1[1]; pu.u[3] = s2[1];
        s16x8 vf0 = *(const s16x8*)&Vs[ lq      *72 + kc*32 + kh*16 + hi*8];
        s16x8 vf1 = *(const s16x8*)&Vs[(32 + lq)*72 + kc*32 + kh*16 + hi*8];
        o0 = mfma3216(vf0, pu.v, o0);
        o1 = mfma3216(vf1, pu.v, o1);
      }
    }
    __syncthreads();
  }

  l += __shfl_xor(l, 32);
  float inv = 1.f / l;
  short* orow = attnv + ((size_t)(b*Nc + qrow))*DIM + h*64;
#pragma unroll
  for (int r = 0; r < 16; r += 2){
    int dv = (r&3) + 8*(r>>2) + 4*hi;          // even; pairs (dv, dv+1)
    *(unsigned*)&orow[dv]      = pkbf(o0[r]*inv, o0[r+1]*inv);
    *(unsigned*)&orow[32 + dv] = pkbf(o1[r]*inv, o1[r+1]*inv);
  }
}

// ============================================================
// out = LayerNorm(a2 + p2) over 1024, fp32 out
// ============================================================
__global__ __launch_bounds__(256) void final_ln(const short* __restrict__ a2, const short* __restrict__ p2,
                                                float* __restrict__ out){
  __shared__ float red[16];
  int row = blockIdx.x, tid = threadIdx.x;
  size_t base = (size_t)row*DIM + tid*4;
  s16x4 a = *(const s16x4*)(a2 + base);
  s16x4 p = *(const s16x4*)(p2 + base);
  float v[4]; float s = 0.f, sq = 0.f;
#pragma unroll
  for (int i = 0; i < 4; ++i){ v[i] = b2f(a[i]) + b2f(p[i]); s += v[i]; sq += v[i]*v[i]; }
#pragma unroll
  for (int m = 1; m < 64; m <<= 1){ s += __shfl_xor(s, m); sq += __shfl_xor(sq, m); }
  int wv = tid >> 6;
  if ((tid & 63) == 0){ red[wv] = s; red[8 + wv] = sq; }
  __syncthreads();
  if (tid == 0){
    float S = red[0] + red[1] + red[2] + red[3];
    float Q = red[8] + red[9] + red[10] + red[11];
    float mu = S * (1.f/1024.f);
    float var = Q * (1.f/1024.f) - mu*mu;
    red[12] = mu; red[13] = rsqrtf(var + 1e-5f);
  }
  __syncthreads();
  float mu = red[12], inv = red[13];
#pragma unroll
  for (int i = 0; i < 4; ++i) out[base + i] = (v[i] - mu) * inv;
}

// ============================================================
extern "C" void kernel_launch(void* const* d_in, const int* in_sizes, int n_in,
                              void* d_out, int out_size, void* d_ws, size_t ws_size,
                              hipStream_t stream){
  const float* x    = (const float*)d_in[0];
  const float* Wqkv = (const float*)d_in[1];
  const float* W1   = (const float*)d_in[2];
  const float* b1   = (const float*)d_in[3];
  const float* W2   = (const float*)d_in[4];
  const float* b2   = (const float*)d_in[5];
  const float* Wout = (const float*)d_in[6];
  const float* bout = (const float*)d_in[7];
  float* out = (float*)d_out;
  char* ws = (char*)d_ws;

  short* xb    = (short*)(ws + OFF_XB);
  short* wqkvt = (short*)(ws + OFF_WQKVT);
  short* w1t   = (short*)(ws + OFF_W1T);
  short* w2t   = (short*)(ws + OFF_W2T);
  short* woutt = (short*)(ws + OFF_WOUTT);
  short* qkv   = (short*)(ws + OFF_QKV);
  short* qln   = (short*)(ws + OFF_QLN);
  short* kln   = (short*)(ws + OFF_KLN);
  short* vtb   = (short*)(ws + OFF_VT);
  short* attnv = (short*)(ws + OFF_ATTNV);
  short* hbuf  = (short*)(ws + OFF_H);
  short* p2    = (short*)(ws + OFF_P2);
  short* a2    = (short*)(ws + OFF_A2);

  conv_x<<<4096, 256, 0, stream>>>(x, xb);
  transpose_conv<<<(DIM/32)*(D3/32),  256, 0, stream>>>(Wqkv, wqkvt, DIM, D3);
  transpose_conv<<<(DIM/32)*(MLP/32), 256, 0, stream>>>(W1, w1t, DIM, MLP);
  transpose_conv<<<(MLP/32)*(DIM/32), 256, 0, stream>>>(W2, w2t, MLP, DIM);
  transpose_conv<<<(DIM/32)*(DIM/32), 256, 0, stream>>>(Wout, woutt, DIM, DIM);

  gemm_bf16<<<(Tc/128)*(D3/128), 256, 0, stream>>>(xb, wqkvt, qkv, nullptr, Tc, D3, DIM, 0);
  ln_reorg<<<64*32, 256, 0, stream>>>(qkv, qln, kln, vtb);
  attn_kern<<<64*16, 256, 0, stream>>>(qln, kln, vtb, attnv);

  gemm_bf16<<<(Tc/128)*(MLP/128), 256, 0, stream>>>(xb, w1t, hbuf, b1, Tc, MLP, DIM, 1);
  gemm_bf16<<<(Tc/128)*(DIM/128), 256, 0, stream>>>(hbuf, w2t, p2, b2, Tc, DIM, MLP, 0);
  gemm_bf16<<<(Tc/128)*(DIM/128), 256, 0, stream>>>(attnv, woutt, a2, bout, Tc, DIM, DIM, 0);

  final_ln<<<Tc, 256, 0, stream>>>(a2, p2, out);
}

// Round 3
// 476.447 us; speedup vs baseline: 1.0627x; 1.0568x over previous
//
#include <hip/hip_runtime.h>

typedef __attribute__((ext_vector_type(8))) short s16x8;
typedef __attribute__((ext_vector_type(4))) short s16x4;
typedef __attribute__((ext_vector_type(4))) float f32x4;
typedef __attribute__((ext_vector_type(16))) float f32x16;
typedef __attribute__((ext_vector_type(2))) unsigned uint2v;

#define DEVINL __device__ __forceinline__

// ---------- bf16 helpers (manual RNE) ----------
DEVINL float b2f(short u){ return __uint_as_float(((unsigned)(unsigned short)u) << 16); }
DEVINL short f2bf(float f){
  unsigned u = __float_as_uint(f);
  u += 0x7fffu + ((u >> 16) & 1u);
  return (short)(u >> 16);
}
DEVINL unsigned pkbf(float a, float b){
  return (unsigned)(unsigned short)f2bf(a) | ((unsigned)(unsigned short)f2bf(b) << 16);
}

#if __has_builtin(__builtin_amdgcn_exp2f)
#define EXP2F __builtin_amdgcn_exp2f
#else
#define EXP2F exp2f
#endif

// ---------- MFMA wrappers ----------
DEVINL f32x4 mfma32(s16x8 a, s16x8 b, f32x4 c){
  // A: m=lane&15, k=8*(lane>>4)+i ; B: n=lane&15, k=8*(lane>>4)+i
  // D: n=lane&15, m=4*(lane>>4)+i   [verified in R1/R2]
  return __builtin_amdgcn_mfma_f32_16x16x32_bf16(a, b, c, 0, 0, 0);
}
DEVINL f32x16 mfma3216(s16x8 a, s16x8 b, f32x16 c){
  // D: col=lane&31, row=(reg&3)+8*(reg>>2)+4*(lane>>5)  [m74/m101; verified in R2]
  return __builtin_amdgcn_mfma_f32_32x32x16_bf16(a, b, c, 0, 0, 0);
}

DEVINL uint2v pl32swap(unsigned a, unsigned b){
#if __has_builtin(__builtin_amdgcn_permlane32_swap)
  return __builtin_amdgcn_permlane32_swap(a, b, false, false);
#else
  asm volatile("v_permlane32_swap_b32 %0, %1" : "+v"(a), "+v"(b));
  uint2v r; r[0] = a; r[1] = b; return r;
#endif
}

// ---------- async global->LDS (width 16) ----------
typedef const unsigned __attribute__((address_space(1)))* gas1;
typedef unsigned __attribute__((address_space(3)))* las3;
DEVINL void gload16(const short* g, short* l){
  // LDS dest: wave-uniform base + lane*16B (m104/m108); global src per-lane.
  __builtin_amdgcn_global_load_lds((gas1)g, (las3)l, 16, 0, 0);
}

// ---------- sync primitives for the pipelined GEMM ----------
#define CFENCE asm volatile("" ::: "memory")
#define PBAR  do{ CFENCE; __builtin_amdgcn_sched_barrier(0); __builtin_amdgcn_s_barrier(); \
                  __builtin_amdgcn_sched_barrier(0); CFENCE; }while(0)
#define VMW4 asm volatile("s_waitcnt vmcnt(4)" ::: "memory")
#define VMW3 asm volatile("s_waitcnt vmcnt(3)" ::: "memory")
#define VMW0 asm volatile("s_waitcnt vmcnt(0)" ::: "memory")

// ---------- problem constants ----------
static const int Bc   = 4;
static const int Nc   = 2048;
static const int DIM  = 1024;
static const int Tc   = Bc * Nc;      // 8192 tokens
static const int MLP  = 4096;
static const int D3   = 3072;

// ---------- ws layout (bytes) ----------
static const size_t OFF_XB    = 0;                         // 8192x1024 bf16
static const size_t OFF_WQKVT = OFF_XB    + 16777216;      // 3072x1024 bf16
static const size_t OFF_W1T   = OFF_WQKVT + 6291456;       // 4096x1024 bf16
static const size_t OFF_W2T   = OFF_W1T   + 8388608;       // 1024x4096 bf16
static const size_t OFF_WOUTT = OFF_W2T   + 8388608;       // 1024x1024 bf16
static const size_t OFF_QKV   = OFF_WOUTT + 2097152;       // 8192x3072 bf16
static const size_t OFF_QLN   = OFF_QKV   + 50331648;      // [64bh][2048][64] bf16
static const size_t OFF_KLN   = OFF_QLN   + 16777216;
static const size_t OFF_VT    = OFF_KLN   + 16777216;      // [64bh][64d][2048] bf16
static const size_t OFF_ATTNV = OFF_VT    + 16777216;      // 8192x1024 bf16
// aliases of dead regions (stream-ordered safe):
static const size_t OFF_H     = OFF_QKV;                   // 8192x4096 bf16
static const size_t OFF_P2    = OFF_KLN;
static const size_t OFF_A2    = OFF_VT;

// ============================================================
// x fp32 -> bf16
// ============================================================
__global__ __launch_bounds__(256) void conv_x(const float* __restrict__ x, short* __restrict__ xb){
  size_t i = ((size_t)blockIdx.x * 256 + threadIdx.x) * 8;
  f32x4 v0 = *(const f32x4*)(x + i);
  f32x4 v1 = *(const f32x4*)(x + i + 4);
  s16x8 o;
#pragma unroll
  for (int j = 0; j < 4; ++j){ o[j] = f2bf(v0[j]); o[4+j] = f2bf(v1[j]); }
  *(s16x8*)(xb + i) = o;
}

// ============================================================
// W[K][N] fp32 -> Wt[N][K] bf16
// ============================================================
__global__ __launch_bounds__(256) void transpose_conv(const float* __restrict__ W, short* __restrict__ Wt,
                                                      int K, int N){
  __shared__ float tile[32][33];
  int ntx = N >> 5;
  int tx = blockIdx.x % ntx, ty = blockIdx.x / ntx;
  int r = threadIdx.x >> 3, c = (threadIdx.x & 7) * 4;
  f32x4 v = *(const f32x4*)(W + (size_t)(ty*32 + r)*N + tx*32 + c);
  tile[r][c] = v[0]; tile[r][c+1] = v[1]; tile[r][c+2] = v[2]; tile[r][c+3] = v[3];
  __syncthreads();
  s16x4 o;
#pragma unroll
  for (int j = 0; j < 4; ++j) o[j] = f2bf(tile[c+j][r]);
  *(s16x4*)(Wt + (size_t)(tx*32 + r)*K + ty*32 + c) = o;
}

// ============================================================
// Deep-pipelined GEMM (T1+T3+T4+T5; conflict-free-by-layout LDS slots).
// C[M][N] = act(A[M][K] @ Bt[N][K]^T + bias). 512 thr = 8 waves (2M x 4N).
// BM=256: per-wave 128x64, 4 phases/K-tile (kk x mh), vmcnt(4) at group end.
// BM=128: per-wave  64x64, 2 phases/K-tile (kk),      vmcnt(3) at group end.
// LDS slots: A(kk[,mh]) = rows x 32cols (8KB), B(kk) = 256 x 32 (16KB),
// double-buffered by K-tile parity. Row stride 64B -> balanced banks, no swizzle.
// Stage targets proven dead: slot's last reader phase < stage phase; readers'
// lgkm waits precede their closing barrier; counted vmcnt certifies landing
// one full group before first ds_read of that tile.
// ============================================================
template<int BM, int ACT>
__global__ __launch_bounds__(512, 2) void gemm8p(const short* __restrict__ A, const short* __restrict__ Bt,
                                                 short* __restrict__ C, const float* __restrict__ bias,
                                                 int M, int N, int K){
  constexpr int MREP = BM/32;
  constexpr int ATOT = (BM==256) ? 32768 : 16384;  // shorts
  __shared__ short lds[ATOT + 32768];
  short* Ab = lds;
  short* Bb = lds + ATOT;

  const int tid = threadIdx.x;
  const int w = tid >> 6, lane = tid & 63;
  const int lr = lane & 15, g = lane >> 4;
  const int wr = w >> 2, wc = w & 3;              // 2 x 4 waves
  const int NT = K >> 6;

  const int nbn = N >> 8;
  const int cpx = gridDim.x >> 3;
  const int bid = (int)blockIdx.x;
  const int sw = (bid & 7)*cpx + (bid >> 3);      // XCD-chunked bijective swizzle
  const int bm = sw / nbn, bn = sw % nbn;

  const int l2 = lane >> 2, cof = (lane & 3)*8;
  const size_t arow = (BM==256) ? (size_t)(bm*256 + (w>>2)*128 + (w&3)*16 + l2)
                                : (size_t)(bm*128 + w*16 + l2);
  const short* ap0 = A  + arow*K + cof;
  const short* bp0 = Bt + (size_t)(bn*256 + w*16 + l2)*K + cof;

  auto stA = [&](int T, int kk, int mh){
    if constexpr (BM==256)
      gload16(ap0 + (size_t)mh*64*K + T*64 + kk*32, Ab + (((T&1)*2+kk)*2+mh)*4096 + w*512);
    else
      gload16(ap0 + T*64 + kk*32, Ab + ((T&1)*2+kk)*4096 + w*512);
  };
  auto stB = [&](int T, int kk, int j){
    gload16(bp0 + (size_t)j*128*K + T*64 + kk*32, Bb + ((T&1)*2+kk)*8192 + j*4096 + w*512);
  };
  auto ldA = [&](int buf, int kk, int mh, int mi)->s16x8{
    const int off = (BM==256) ? (((buf*2+kk)*2+mh)*4096) : ((buf*2+kk)*4096);
    return *(const s16x8*)&Ab[off + (wr*64 + mi*16 + lr)*32 + g*8];
  };
  auto ldB = [&](int buf, int kk, int ni)->s16x8{
    return *(const s16x8*)&Bb[(buf*2+kk)*8192 + (wc*64 + ni*16 + lr)*32 + g*8];
  };

  f32x4 acc[MREP][4] = {};

#define MMROW(ai, r) \
  acc[r][0]=mfma32(ai,b0,acc[r][0]); acc[r][1]=mfma32(ai,b1,acc[r][1]); \
  acc[r][2]=mfma32(ai,b2,acc[r][2]); acc[r][3]=mfma32(ai,b3,acc[r][3]);

  // ---- prologue: tile0 fully + tile1 k0-half; counted wait so tile0 is home ----
  if constexpr (BM==256){
    stA(0,0,0); stA(0,0,1); stB(0,0,0); stB(0,0,1);
    stA(0,1,0); stA(0,1,1); stB(0,1,0); stB(0,1,1);
    stA(1,0,0); stA(1,0,1); stB(1,0,0); stB(1,0,1);
    VMW4;
  } else {
    stA(0,0,0); stB(0,0,0); stB(0,0,1);
    stA(0,1,0); stB(0,1,0); stB(0,1,1);
    stA(1,0,0); stB(1,0,0); stB(1,0,1);
    VMW3;
  }
  PBAR;

  for (int t = 0; t < NT; ++t){
    const int buf = t & 1;
    const bool s1 = (t+1 < NT), s2 = (t+2 < NT);

    if constexpr (BM==256){
      { // phase 1: (k0,m0) ; stage t+1 A(k1,*)  [other buf; dead since G(t-1)p4]
        s16x8 a0=ldA(buf,0,0,0), a1=ldA(buf,0,0,1), a2=ldA(buf,0,0,2), a3=ldA(buf,0,0,3);
        s16x8 b0=ldB(buf,0,0), b1=ldB(buf,0,1), b2=ldB(buf,0,2), b3=ldB(buf,0,3);
        if (s1){ stA(t+1,1,0); stA(t+1,1,1); }
        PBAR;
        __builtin_amdgcn_s_setprio(1);
        MMROW(a0,0) MMROW(a1,1) MMROW(a2,2) MMROW(a3,3)
        __builtin_amdgcn_s_setprio(0);
        PBAR;
      }
      { // phase 2: (k0,m1) ; stage t+1 B(k1)
        s16x8 a0=ldA(buf,0,1,0), a1=ldA(buf,0,1,1), a2=ldA(buf,0,1,2), a3=ldA(buf,0,1,3);
        s16x8 b0=ldB(buf,0,0), b1=ldB(buf,0,1), b2=ldB(buf,0,2), b3=ldB(buf,0,3);
        if (s1){ stB(t+1,1,0); stB(t+1,1,1); }
        PBAR;
        __builtin_amdgcn_s_setprio(1);
        MMROW(a0,4) MMROW(a1,5) MMROW(a2,6) MMROW(a3,7)
        __builtin_amdgcn_s_setprio(0);
        PBAR;
      }
      { // phase 3: (k1,m0) ; stage t+2 A(k0,*)  [this buf; A(k0) dead after p1]
        s16x8 a0=ldA(buf,1,0,0), a1=ldA(buf,1,0,1), a2=ldA(buf,1,0,2), a3=ldA(buf,1,0,3);
        s16x8 b0=ldB(buf,1,0), b1=ldB(buf,1,1), b2=ldB(buf,1,2), b3=ldB(buf,1,3);
        if (s2){ stA(t+2,0,0); stA(t+2,0,1); }
        PBAR;
        __builtin_amdgcn_s_setprio(1);
        MMROW(a0,0) MMROW(a1,1) MMROW(a2,2) MMROW(a3,3)
        __builtin_amdgcn_s_setprio(0);
        PBAR;
      }
      { // phase 4: (k1,m1) ; stage t+2 B(k0) ; counted vmcnt certifies tile t+1
        s16x8 a0=ldA(buf,1,1,0), a1=ldA(buf,1,1,1), a2=ldA(buf,1,1,2), a3=ldA(buf,1,1,3);
        s16x8 b0=ldB(buf,1,0), b1=ldB(buf,1,1), b2=ldB(buf,1,2), b3=ldB(buf,1,3);
        if (s2){ stB(t+2,0,0); stB(t+2,0,1); }
        PBAR;
        __builtin_amdgcn_s_setprio(1);
        MMROW(a0,4) MMROW(a1,5) MMROW(a2,6) MMROW(a3,7)
        __builtin_amdgcn_s_setprio(0);
        if (s2){ VMW4; } else { VMW0; }
        PBAR;
      }
    } else {
      { // phase 1: kk=0 ; stage t+1 {A(k1),B(k1)}  [other buf; dead since G(t-1)p2]
        s16x8 a0=ldA(buf,0,0,0), a1=ldA(buf,0,0,1), a2=ldA(buf,0,0,2), a3=ldA(buf,0,0,3);
        s16x8 b0=ldB(buf,0,0), b1=ldB(buf,0,1), b2=ldB(buf,0,2), b3=ldB(buf,0,3);
        if (s1){ stA(t+1,1,0); stB(t+1,1,0); stB(t+1,1,1); }
        PBAR;
        __builtin_amdgcn_s_setprio(1);
        MMROW(a0,0) MMROW(a1,1) MMROW(a2,2) MMROW(a3,3)
        __builtin_amdgcn_s_setprio(0);
        PBAR;
      }
      { // phase 2: kk=1 ; stage t+2 {A(k0),B(k0)} [this buf; k0 dead after p1]
        s16x8 a0=ldA(buf,1,0,0), a1=ldA(buf,1,0,1), a2=ldA(buf,1,0,2), a3=ldA(buf,1,0,3);
        s16x8 b0=ldB(buf,1,0), b1=ldB(buf,1,1), b2=ldB(buf,1,2), b3=ldB(buf,1,3);
        if (s2){ stA(t+2,0,0); stB(t+2,0,0); stB(t+2,0,1); }
        PBAR;
        __builtin_amdgcn_s_setprio(1);
        MMROW(a0,0) MMROW(a1,1) MMROW(a2,2) MMROW(a3,3)
        __builtin_amdgcn_s_setprio(0);
        if (s2){ VMW3; } else { VMW0; }
        PBAR;
      }
    }
  }
#undef MMROW

  // ---- epilogue ----
#pragma unroll
  for (int ni = 0; ni < 4; ++ni){
    const int col = bn*256 + wc*64 + ni*16 + lr;
    const float bv = bias ? bias[col] : 0.f;
#pragma unroll
    for (int a = 0; a < MREP; ++a){
      const int row0 = bm*BM + wr*(BM/2) + a*16 + 4*g;
      f32x4 v = acc[a][ni];
#pragma unroll
      for (int i = 0; i < 4; ++i){
        float val = v[i] + bv;
        if constexpr (ACT) val = 0.5f*val*(1.f + erff(val*0.70710678118f));
        C[(size_t)(row0+i)*N + col] = f2bf(val);
      }
    }
  }
}

// ============================================================
// q/k LayerNorm (d=64) + head-reorg; v -> Vt [bh][d][n]
// q scaled by dim^-0.5 * log2(e)  (exp2-domain softmax)
// ============================================================
__global__ __launch_bounds__(256) void ln_reorg(const short* __restrict__ qkv, short* __restrict__ qln,
                                                short* __restrict__ kln, short* __restrict__ vtb){
  __shared__ short vtile[64*72];
  int bh = blockIdx.x >> 5, tch = blockIdx.x & 31;
  int b = bh >> 4, h = bh & 15;
  int tq = threadIdx.x >> 2, j = threadIdx.x & 3;
  size_t row = (size_t)b*Nc + tch*64 + tq;
  const short* base = qkv + row*D3 + h*64 + j*16;
  size_t orow = ((size_t)bh*Nc + tch*64 + tq)*64 + j*16;

#pragma unroll
  for (int part = 0; part < 2; ++part){
    const short* src = base + part*DIM;
    s16x8 u0 = *(const s16x8*)src;
    s16x8 u1 = *(const s16x8*)(src + 8);
    float f[16]; float s = 0.f, sq = 0.f;
#pragma unroll
    for (int i = 0; i < 8; ++i){ f[i] = b2f(u0[i]); f[8+i] = b2f(u1[i]); }
#pragma unroll
    for (int i = 0; i < 16; ++i){ s += f[i]; sq += f[i]*f[i]; }
    s  += __shfl_xor(s, 1);  s  += __shfl_xor(s, 2);
    sq += __shfl_xor(sq, 1); sq += __shfl_xor(sq, 2);
    float mu = s * (1.f/64.f);
    float var = sq * (1.f/64.f) - mu*mu;
    float inv = rsqrtf(var + 1e-5f) * (part == 0 ? 0.04508422003f : 1.f);
    s16x8 o0, o1;
#pragma unroll
    for (int i = 0; i < 8; ++i){ o0[i] = f2bf((f[i]-mu)*inv); o1[i] = f2bf((f[8+i]-mu)*inv); }
    short* dst = (part == 0 ? qln : kln) + orow;
    *(s16x8*)dst = o0; *(s16x8*)(dst + 8) = o1;
  }

  s16x8 v0 = *(const s16x8*)(base + 2*DIM);
  s16x8 v1 = *(const s16x8*)(base + 2*DIM + 8);
  *(s16x8*)&vtile[tq*72 + j*16]     = v0;
  *(s16x8*)&vtile[tq*72 + j*16 + 8] = v1;
  __syncthreads();
  s16x8 o0, o1;
#pragma unroll
  for (int i = 0; i < 8; ++i){
    o0[i] = vtile[(j*16 + i)*72 + tq];
    o1[i] = vtile[(j*16 + 8 + i)*72 + tq];
  }
  short* vdst = vtb + ((size_t)bh*64 + tq)*Nc + tch*64 + j*16;
  *(s16x8*)vdst = o0; *(s16x8*)(vdst + 8) = o1;
}

// ============================================================
// Flash attention, 32x32 swapped form (working R2 version, unchanged).
// ============================================================
__global__ __launch_bounds__(256) void attn_kern(const short* __restrict__ qln, const short* __restrict__ kln,
                                                 const short* __restrict__ vtb, short* __restrict__ attnv){
  __shared__ short Ks[64*72];
  __shared__ short Vs[64*72];
  int bh = blockIdx.x >> 4, qt = blockIdx.x & 15;
  int b = bh >> 4, h = bh & 15;
  int w = threadIdx.x >> 6, lane = threadIdx.x & 63;
  int lq = lane & 31, hi = lane >> 5;
  int qrow = qt*128 + w*32 + lq;

  const short* qp = qln + ((size_t)bh*Nc + qrow)*64 + hi*8;
  s16x8 qf[4];
#pragma unroll
  for (int m = 0; m < 4; ++m) qf[m] = *(const s16x8*)(qp + m*16);

  f32x16 o0 = {0,0,0,0,0,0,0,0,0,0,0,0,0,0,0,0};
  f32x16 o1 = {0,0,0,0,0,0,0,0,0,0,0,0,0,0,0,0};
  float mrun = -INFINITY, l = 0.f;

  int tr = threadIdx.x >> 2, seg = (threadIdx.x & 3) * 16;
  const short* kbase = kln + ((size_t)bh*Nc + tr)*64 + seg;
  const short* vbase = vtb + ((size_t)bh*64 + tr)*Nc + seg;
  short* ksd = &Ks[tr*72 + seg];
  short* vsd = &Vs[tr*72 + seg];

  for (int kt = 0; kt < Nc; kt += 64){
    const short* ksrc = kbase + (size_t)kt*64;
    *(s16x8*)ksd       = *(const s16x8*)ksrc;
    *(s16x8*)(ksd + 8) = *(const s16x8*)(ksrc + 8);
    const short* vsrc = vbase + kt;
    *(s16x8*)vsd       = *(const s16x8*)vsrc;
    *(s16x8*)(vsd + 8) = *(const s16x8*)(vsrc + 8);
    __syncthreads();

#pragma unroll
    for (int kc = 0; kc < 2; ++kc){
      f32x16 st = {0,0,0,0,0,0,0,0,0,0,0,0,0,0,0,0};
#pragma unroll
      for (int m = 0; m < 4; ++m){
        s16x8 kf = *(const s16x8*)&Ks[(kc*32 + lq)*72 + m*16 + hi*8];
        st = mfma3216(kf, qf[m], st);
      }
      float cmax = st[0];
#pragma unroll
      for (int r = 1; r < 16; ++r) cmax = fmaxf(cmax, st[r]);
      cmax = fmaxf(cmax, __shfl_xor(cmax, 32));
      if (__any(cmax > mrun + 8.f)){
        float mnew = fmaxf(mrun, cmax);
        float fr = EXP2F(mrun - mnew);
        l *= fr;
#pragma unroll
        for (int r = 0; r < 16; ++r){ o0[r] *= fr; o1[r] *= fr; }
        mrun = mnew;
      }
      float p[16];
#pragma unroll
      for (int r = 0; r < 16; ++r){ p[r] = EXP2F(st[r] - mrun); l += p[r]; }

#pragma unroll
      for (int kh = 0; kh < 2; ++kh){
        int r0 = kh*8;
        unsigned wa = pkbf(p[r0+0], p[r0+1]);
        unsigned wb = pkbf(p[r0+4], p[r0+5]);
        unsigned wc2 = pkbf(p[r0+2], p[r0+3]);
        unsigned wd = pkbf(p[r0+6], p[r0+7]);
        uint2v s1 = pl32swap(wa, wb);
        uint2v s2 = pl32swap(wc2, wd);
        union { unsigned u[4]; s16x8 v; } pu;
        pu.u[0] = s1[0]; pu.u[1] = s2[0]; pu.u[2] = s1[1]; pu.u[3] = s2[1];
        s16x8 vf0 = *(const s16x8*)&Vs[ lq      *72 + kc*32 + kh*16 + hi*8];
        s16x8 vf1 = *(const s16x8*)&Vs[(32 + lq)*72 + kc*32 + kh*16 + hi*8];
        o0 = mfma3216(vf0, pu.v, o0);
        o1 = mfma3216(vf1, pu.v, o1);
      }
    }
    __syncthreads();
  }

  l += __shfl_xor(l, 32);
  float inv = 1.f / l;
  short* orow = attnv + ((size_t)(b*Nc + qrow))*DIM + h*64;
#pragma unroll
  for (int r = 0; r < 16; r += 2){
    int dv = (r&3) + 8*(r>>2) + 4*hi;
    *(unsigned*)&orow[dv]      = pkbf(o0[r]*inv, o0[r+1]*inv);
    *(unsigned*)&orow[32 + dv] = pkbf(o1[r]*inv, o1[r+1]*inv);
  }
}

// ============================================================
// out = LayerNorm(a2 + p2) over 1024, fp32 out
// ============================================================
__global__ __launch_bounds__(256) void final_ln(const short* __restrict__ a2, const short* __restrict__ p2,
                                                float* __restrict__ out){
  __shared__ float red[16];
  int row = blockIdx.x, tid = threadIdx.x;
  size_t base = (size_t)row*DIM + tid*4;
  s16x4 a = *(const s16x4*)(a2 + base);
  s16x4 p = *(const s16x4*)(p2 + base);
  float v[4]; float s = 0.f, sq = 0.f;
#pragma unroll
  for (int i = 0; i < 4; ++i){ v[i] = b2f(a[i]) + b2f(p[i]); s += v[i]; sq += v[i]*v[i]; }
#pragma unroll
  for (int m = 1; m < 64; m <<= 1){ s += __shfl_xor(s, m); sq += __shfl_xor(sq, m); }
  int wv = tid >> 6;
  if ((tid & 63) == 0){ red[wv] = s; red[8 + wv] = sq; }
  __syncthreads();
  if (tid == 0){
    float S = red[0] + red[1] + red[2] + red[3];
    float Q = red[8] + red[9] + red[10] + red[11];
    float mu = S * (1.f/1024.f);
    float var = Q * (1.f/1024.f) - mu*mu;
    red[12] = mu; red[13] = rsqrtf(var + 1e-5f);
  }
  __syncthreads();
  float mu = red[12], inv = red[13];
#pragma unroll
  for (int i = 0; i < 4; ++i) out[base + i] = (v[i] - mu) * inv;
}

// ============================================================
extern "C" void kernel_launch(void* const* d_in, const int* in_sizes, int n_in,
                              void* d_out, int out_size, void* d_ws, size_t ws_size,
                              hipStream_t stream){
  const float* x    = (const float*)d_in[0];
  const float* Wqkv = (const float*)d_in[1];
  const float* W1   = (const float*)d_in[2];
  const float* b1   = (const float*)d_in[3];
  const float* W2   = (const float*)d_in[4];
  const float* b2   = (const float*)d_in[5];
  const float* Wout = (const float*)d_in[6];
  const float* bout = (const float*)d_in[7];
  float* out = (float*)d_out;
  char* ws = (char*)d_ws;

  short* xb    = (short*)(ws + OFF_XB);
  short* wqkvt = (short*)(ws + OFF_WQKVT);
  short* w1t   = (short*)(ws + OFF_W1T);
  short* w2t   = (short*)(ws + OFF_W2T);
  short* woutt = (short*)(ws + OFF_WOUTT);
  short* qkv   = (short*)(ws + OFF_QKV);
  short* qln   = (short*)(ws + OFF_QLN);
  short* kln   = (short*)(ws + OFF_KLN);
  short* vtb   = (short*)(ws + OFF_VT);
  short* attnv = (short*)(ws + OFF_ATTNV);
  short* hbuf  = (short*)(ws + OFF_H);
  short* p2    = (short*)(ws + OFF_P2);
  short* a2    = (short*)(ws + OFF_A2);

  conv_x<<<4096, 256, 0, stream>>>(x, xb);
  transpose_conv<<<(DIM/32)*(D3/32),  256, 0, stream>>>(Wqkv, wqkvt, DIM, D3);
  transpose_conv<<<(DIM/32)*(MLP/32), 256, 0, stream>>>(W1, w1t, DIM, MLP);
  transpose_conv<<<(MLP/32)*(DIM/32), 256, 0, stream>>>(W2, w2t, MLP, DIM);
  transpose_conv<<<(DIM/32)*(DIM/32), 256, 0, stream>>>(Wout, woutt, DIM, DIM);

  gemm8p<256,0><<<(Tc/256)*(D3/256), 512, 0, stream>>>(xb, wqkvt, qkv, nullptr, Tc, D3, DIM);
  ln_reorg<<<64*32, 256, 0, stream>>>(qkv, qln, kln, vtb);
  attn_kern<<<64*16, 256, 0, stream>>>(qln, kln, vtb, attnv);

  gemm8p<256,1><<<(Tc/256)*(MLP/256), 512, 0, stream>>>(xb, w1t, hbuf, b1, Tc, MLP, DIM);
  gemm8p<128,0><<<(Tc/128)*(DIM/256), 512, 0, stream>>>(hbuf, w2t, p2, b2, Tc, DIM, MLP);
  gemm8p<128,0><<<(Tc/128)*(DIM/256), 512, 0, stream>>>(attnv, woutt, a2, bout, Tc, DIM, DIM);

  final_ln<<<Tc, 256, 0, stream>>>(a2, p2, out);
}

// Round 4
// 441.038 us; speedup vs baseline: 1.1481x; 1.0803x over previous
//
#include <hip/hip_runtime.h>

typedef __attribute__((ext_vector_type(8))) short s16x8;
typedef __attribute__((ext_vector_type(4))) short s16x4;
typedef __attribute__((ext_vector_type(4))) float f32x4;
typedef __attribute__((ext_vector_type(16))) float f32x16;
typedef __attribute__((ext_vector_type(2))) unsigned uint2v;

#define DEVINL __device__ __forceinline__

// ---------- bf16 helpers (manual RNE) ----------
DEVINL float b2f(short u){ return __uint_as_float(((unsigned)(unsigned short)u) << 16); }
DEVINL short f2bf(float f){
  unsigned u = __float_as_uint(f);
  u += 0x7fffu + ((u >> 16) & 1u);
  return (short)(u >> 16);
}
DEVINL unsigned pkbf(float a, float b){
  return (unsigned)(unsigned short)f2bf(a) | ((unsigned)(unsigned short)f2bf(b) << 16);
}

#if __has_builtin(__builtin_amdgcn_exp2f)
#define EXP2F __builtin_amdgcn_exp2f
#else
#define EXP2F exp2f
#endif

// ---------- MFMA wrappers ----------
DEVINL f32x4 mfma32(s16x8 a, s16x8 b, f32x4 c){
  // A: m=lane&15, k=8*(lane>>4)+i ; B: n=lane&15, k=8*(lane>>4)+i
  // D: n=lane&15, m=4*(lane>>4)+i   [verified R1/R2]
  return __builtin_amdgcn_mfma_f32_16x16x32_bf16(a, b, c, 0, 0, 0);
}
DEVINL f32x16 mfma3216(s16x8 a, s16x8 b, f32x16 c){
  // D: col=lane&31, row=(reg&3)+8*(reg>>2)+4*(lane>>5)  [verified R2]
  return __builtin_amdgcn_mfma_f32_32x32x16_bf16(a, b, c, 0, 0, 0);
}

DEVINL uint2v pl32swap(unsigned a, unsigned b){
#if __has_builtin(__builtin_amdgcn_permlane32_swap)
  return __builtin_amdgcn_permlane32_swap(a, b, false, false);
#else
  asm volatile("v_permlane32_swap_b32 %0, %1" : "+v"(a), "+v"(b));
  uint2v r; r[0] = a; r[1] = b; return r;
#endif
}

// ---------- async global->LDS (width 16) ----------
typedef const unsigned __attribute__((address_space(1)))* gas1;
typedef unsigned __attribute__((address_space(3)))* las3;
DEVINL void gload16(const short* g, short* l){
  __builtin_amdgcn_global_load_lds((gas1)g, (las3)l, 16, 0, 0);
}

// ---------- sync primitives ----------
#define CFENCE asm volatile("" ::: "memory")
#define PBAR  do{ CFENCE; __builtin_amdgcn_sched_barrier(0); __builtin_amdgcn_s_barrier(); \
                  __builtin_amdgcn_sched_barrier(0); CFENCE; }while(0)
#define VMW4 asm volatile("s_waitcnt vmcnt(4)" ::: "memory")
#define VMW3 asm volatile("s_waitcnt vmcnt(3)" ::: "memory")
#define VMW0 asm volatile("s_waitcnt vmcnt(0)" ::: "memory")

// ---------- problem constants ----------
static const int Bc   = 4;
static const int Nc   = 2048;
static const int DIM  = 1024;
static const int Tc   = Bc * Nc;      // 8192 tokens
static const int MLP  = 4096;
static const int D3   = 3072;

// ---------- ws layout (bytes) ----------
static const size_t OFF_XB    = 0;
static const size_t OFF_WQKVT = OFF_XB    + 16777216;
static const size_t OFF_W1T   = OFF_WQKVT + 6291456;
static const size_t OFF_W2T   = OFF_W1T   + 8388608;
static const size_t OFF_WOUTT = OFF_W2T   + 8388608;
static const size_t OFF_QKV   = OFF_WOUTT + 2097152;
static const size_t OFF_QLN   = OFF_QKV   + 50331648;
static const size_t OFF_KLN   = OFF_QLN   + 16777216;
static const size_t OFF_VT    = OFF_KLN   + 16777216;
static const size_t OFF_ATTNV = OFF_VT    + 16777216;
static const size_t OFF_H     = OFF_QKV;   // aliases of dead regions
static const size_t OFF_P2    = OFF_KLN;
static const size_t OFF_A2    = OFF_VT;

// ============================================================
// x fp32 -> bf16
// ============================================================
__global__ __launch_bounds__(256) void conv_x(const float* __restrict__ x, short* __restrict__ xb){
  size_t i = ((size_t)blockIdx.x * 256 + threadIdx.x) * 8;
  f32x4 v0 = *(const f32x4*)(x + i);
  f32x4 v1 = *(const f32x4*)(x + i + 4);
  s16x8 o;
#pragma unroll
  for (int j = 0; j < 4; ++j){ o[j] = f2bf(v0[j]); o[4+j] = f2bf(v1[j]); }
  *(s16x8*)(xb + i) = o;
}

// ============================================================
// W[K][N] fp32 -> Wt[N][K] bf16
// ============================================================
__global__ __launch_bounds__(256) void transpose_conv(const float* __restrict__ W, short* __restrict__ Wt,
                                                      int K, int N){
  __shared__ float tile[32][33];
  int ntx = N >> 5;
  int tx = blockIdx.x % ntx, ty = blockIdx.x / ntx;
  int r = threadIdx.x >> 3, c = (threadIdx.x & 7) * 4;
  f32x4 v = *(const f32x4*)(W + (size_t)(ty*32 + r)*N + tx*32 + c);
  tile[r][c] = v[0]; tile[r][c+1] = v[1]; tile[r][c+2] = v[2]; tile[r][c+3] = v[3];
  __syncthreads();
  s16x4 o;
#pragma unroll
  for (int j = 0; j < 4; ++j) o[j] = f2bf(tile[c+j][r]);
  *(s16x4*)(Wt + (size_t)(tx*32 + r)*K + ty*32 + c) = o;
}

// ============================================================
// Deep-pipelined GEMM (T1+T3+T4+T5) with k-group LDS swizzle.
// Swizzle: element (row, g) stored at col-slot q=(g+(row>>1))&3 of its 64B row.
//   -> every 8-lane b128 pass hits 8 distinct bank-quads (conflict-free).
//   LDS dest stays LINEAR (global_load_lds constraint); the global SOURCE
//   address is inverse-permuted per lane; both offsets are loop-invariant.
// ============================================================
template<int BM, int ACT>
__global__ __launch_bounds__(512, 2) void gemm8p(const short* __restrict__ A, const short* __restrict__ Bt,
                                                 short* __restrict__ C, const float* __restrict__ bias,
                                                 int M, int N, int K){
  constexpr int MREP = BM/32;
  constexpr int ATOT = (BM==256) ? 32768 : 16384;  // shorts
  __shared__ short lds[ATOT + 32768];
  short* Ab = lds;
  short* Bb = lds + ATOT;

  const int tid = threadIdx.x;
  const int w = tid >> 6, lane = tid & 63;
  const int lr = lane & 15, g = lane >> 4;
  const int wr = w >> 2, wc = w & 3;              // 2 x 4 waves
  const int NT = K >> 6;

  const int nbn = N >> 8;
  const int cpx = gridDim.x >> 3;
  const int bid = (int)blockIdx.x;
  const int sw = (bid & 7)*cpx + (bid >> 3);      // XCD-chunked bijective swizzle
  const int bm = sw / nbn, bn = sw % nbn;

  // staging: lane loads global k-group gsw of row l2 -> lands at linear LDS
  // slot (row l2, col-slot lane&3); inverse of the read swizzle.
  const int l2 = lane >> 2;
  const int gsw = ((lane & 3) - ((lane >> 3) & 3)) & 3;
  const int cof = gsw * 8;
  // read: k-group g of row (..+lr) sits at col-slot qsw=(g+(lr>>1))&3
  const int qsw8 = (((g + (lr >> 1)) & 3)) * 8;

  const size_t arow = (BM==256) ? (size_t)(bm*256 + (w>>2)*128 + (w&3)*16 + l2)
                                : (size_t)(bm*128 + w*16 + l2);
  const short* ap0 = A  + arow*K + cof;
  const short* bp0 = Bt + (size_t)(bn*256 + w*16 + l2)*K + cof;

  auto stA = [&](int T, int kk, int mh){
    if constexpr (BM==256)
      gload16(ap0 + (size_t)mh*64*K + T*64 + kk*32, Ab + (((T&1)*2+kk)*2+mh)*4096 + w*512);
    else
      gload16(ap0 + T*64 + kk*32, Ab + ((T&1)*2+kk)*4096 + w*512);
  };
  auto stB = [&](int T, int kk, int j){
    gload16(bp0 + (size_t)j*128*K + T*64 + kk*32, Bb + ((T&1)*2+kk)*8192 + j*4096 + w*512);
  };
  auto ldA = [&](int buf, int kk, int mh, int mi)->s16x8{
    const int off = (BM==256) ? (((buf*2+kk)*2+mh)*4096) : ((buf*2+kk)*4096);
    return *(const s16x8*)&Ab[off + (wr*64 + mi*16 + lr)*32 + qsw8];
  };
  auto ldB = [&](int buf, int kk, int ni)->s16x8{
    return *(const s16x8*)&Bb[(buf*2+kk)*8192 + (wc*64 + ni*16 + lr)*32 + qsw8];
  };

  f32x4 acc[MREP][4] = {};

#define MMROW(ai, r) \
  acc[r][0]=mfma32(ai,b0,acc[r][0]); acc[r][1]=mfma32(ai,b1,acc[r][1]); \
  acc[r][2]=mfma32(ai,b2,acc[r][2]); acc[r][3]=mfma32(ai,b3,acc[r][3]);

  // ---- prologue ----
  if constexpr (BM==256){
    stA(0,0,0); stA(0,0,1); stB(0,0,0); stB(0,0,1);
    stA(0,1,0); stA(0,1,1); stB(0,1,0); stB(0,1,1);
    stA(1,0,0); stA(1,0,1); stB(1,0,0); stB(1,0,1);
    VMW4;
  } else {
    stA(0,0,0); stB(0,0,0); stB(0,0,1);
    stA(0,1,0); stB(0,1,0); stB(0,1,1);
    stA(1,0,0); stB(1,0,0); stB(1,0,1);
    VMW3;
  }
  PBAR;

  for (int t = 0; t < NT; ++t){
    const int buf = t & 1;
    const bool s1 = (t+1 < NT), s2 = (t+2 < NT);

    if constexpr (BM==256){
      { // phase 1: (k0,m0) ; stage t+1 A(k1,*)
        s16x8 a0=ldA(buf,0,0,0), a1=ldA(buf,0,0,1), a2=ldA(buf,0,0,2), a3=ldA(buf,0,0,3);
        s16x8 b0=ldB(buf,0,0), b1=ldB(buf,0,1), b2=ldB(buf,0,2), b3=ldB(buf,0,3);
        if (s1){ stA(t+1,1,0); stA(t+1,1,1); }
        PBAR;
        __builtin_amdgcn_s_setprio(1);
        MMROW(a0,0) MMROW(a1,1) MMROW(a2,2) MMROW(a3,3)
        __builtin_amdgcn_s_setprio(0);
        PBAR;
      }
      { // phase 2: (k0,m1) ; stage t+1 B(k1)
        s16x8 a0=ldA(buf,0,1,0), a1=ldA(buf,0,1,1), a2=ldA(buf,0,1,2), a3=ldA(buf,0,1,3);
        s16x8 b0=ldB(buf,0,0), b1=ldB(buf,0,1), b2=ldB(buf,0,2), b3=ldB(buf,0,3);
        if (s1){ stB(t+1,1,0); stB(t+1,1,1); }
        PBAR;
        __builtin_amdgcn_s_setprio(1);
        MMROW(a0,4) MMROW(a1,5) MMROW(a2,6) MMROW(a3,7)
        __builtin_amdgcn_s_setprio(0);
        PBAR;
      }
      { // phase 3: (k1,m0) ; stage t+2 A(k0,*)
        s16x8 a0=ldA(buf,1,0,0), a1=ldA(buf,1,0,1), a2=ldA(buf,1,0,2), a3=ldA(buf,1,0,3);
        s16x8 b0=ldB(buf,1,0), b1=ldB(buf,1,1), b2=ldB(buf,1,2), b3=ldB(buf,1,3);
        if (s2){ stA(t+2,0,0); stA(t+2,0,1); }
        PBAR;
        __builtin_amdgcn_s_setprio(1);
        MMROW(a0,0) MMROW(a1,1) MMROW(a2,2) MMROW(a3,3)
        __builtin_amdgcn_s_setprio(0);
        PBAR;
      }
      { // phase 4: (k1,m1) ; stage t+2 B(k0) ; counted vmcnt
        s16x8 a0=ldA(buf,1,1,0), a1=ldA(buf,1,1,1), a2=ldA(buf,1,1,2), a3=ldA(buf,1,1,3);
        s16x8 b0=ldB(buf,1,0), b1=ldB(buf,1,1), b2=ldB(buf,1,2), b3=ldB(buf,1,3);
        if (s2){ stB(t+2,0,0); stB(t+2,0,1); }
        PBAR;
        __builtin_amdgcn_s_setprio(1);
        MMROW(a0,4) MMROW(a1,5) MMROW(a2,6) MMROW(a3,7)
        __builtin_amdgcn_s_setprio(0);
        if (s2){ VMW4; } else { VMW0; }
        PBAR;
      }
    } else {
      { // phase 1: kk=0 ; stage t+1 {A(k1),B(k1)}
        s16x8 a0=ldA(buf,0,0,0), a1=ldA(buf,0,0,1), a2=ldA(buf,0,0,2), a3=ldA(buf,0,0,3);
        s16x8 b0=ldB(buf,0,0), b1=ldB(buf,0,1), b2=ldB(buf,0,2), b3=ldB(buf,0,3);
        if (s1){ stA(t+1,1,0); stB(t+1,1,0); stB(t+1,1,1); }
        PBAR;
        __builtin_amdgcn_s_setprio(1);
        MMROW(a0,0) MMROW(a1,1) MMROW(a2,2) MMROW(a3,3)
        __builtin_amdgcn_s_setprio(0);
        PBAR;
      }
      { // phase 2: kk=1 ; stage t+2 {A(k0),B(k0)}
        s16x8 a0=ldA(buf,1,0,0), a1=ldA(buf,1,0,1), a2=ldA(buf,1,0,2), a3=ldA(buf,1,0,3);
        s16x8 b0=ldB(buf,1,0), b1=ldB(buf,1,1), b2=ldB(buf,1,2), b3=ldB(buf,1,3);
        if (s2){ stA(t+2,0,0); stB(t+2,0,0); stB(t+2,0,1); }
        PBAR;
        __builtin_amdgcn_s_setprio(1);
        MMROW(a0,0) MMROW(a1,1) MMROW(a2,2) MMROW(a3,3)
        __builtin_amdgcn_s_setprio(0);
        if (s2){ VMW3; } else { VMW0; }
        PBAR;
      }
    }
  }
#undef MMROW

  // ---- epilogue ----
#pragma unroll
  for (int ni = 0; ni < 4; ++ni){
    const int col = bn*256 + wc*64 + ni*16 + lr;
    const float bv = bias ? bias[col] : 0.f;
#pragma unroll
    for (int a = 0; a < MREP; ++a){
      const int row0 = bm*BM + wr*(BM/2) + a*16 + 4*g;
      f32x4 v = acc[a][ni];
#pragma unroll
      for (int i = 0; i < 4; ++i){
        float val = v[i] + bv;
        if constexpr (ACT) val = 0.5f*val*(1.f + erff(val*0.70710678118f));
        C[(size_t)(row0+i)*N + col] = f2bf(val);
      }
    }
  }
}

// ============================================================
// q/k LayerNorm (d=64) + head-reorg; v -> Vt [bh][d][n]
// ============================================================
__global__ __launch_bounds__(256) void ln_reorg(const short* __restrict__ qkv, short* __restrict__ qln,
                                                short* __restrict__ kln, short* __restrict__ vtb){
  __shared__ short vtile[64*72];
  int bh = blockIdx.x >> 5, tch = blockIdx.x & 31;
  int b = bh >> 4, h = bh & 15;
  int tq = threadIdx.x >> 2, j = threadIdx.x & 3;
  size_t row = (size_t)b*Nc + tch*64 + tq;
  const short* base = qkv + row*D3 + h*64 + j*16;
  size_t orow = ((size_t)bh*Nc + tch*64 + tq)*64 + j*16;

#pragma unroll
  for (int part = 0; part < 2; ++part){
    const short* src = base + part*DIM;
    s16x8 u0 = *(const s16x8*)src;
    s16x8 u1 = *(const s16x8*)(src + 8);
    float f[16]; float s = 0.f, sq = 0.f;
#pragma unroll
    for (int i = 0; i < 8; ++i){ f[i] = b2f(u0[i]); f[8+i] = b2f(u1[i]); }
#pragma unroll
    for (int i = 0; i < 16; ++i){ s += f[i]; sq += f[i]*f[i]; }
    s  += __shfl_xor(s, 1);  s  += __shfl_xor(s, 2);
    sq += __shfl_xor(sq, 1); sq += __shfl_xor(sq, 2);
    float mu = s * (1.f/64.f);
    float var = sq * (1.f/64.f) - mu*mu;
    float inv = rsqrtf(var + 1e-5f) * (part == 0 ? 0.04508422003f : 1.f);
    s16x8 o0, o1;
#pragma unroll
    for (int i = 0; i < 8; ++i){ o0[i] = f2bf((f[i]-mu)*inv); o1[i] = f2bf((f[8+i]-mu)*inv); }
    short* dst = (part == 0 ? qln : kln) + orow;
    *(s16x8*)dst = o0; *(s16x8*)(dst + 8) = o1;
  }

  s16x8 v0 = *(const s16x8*)(base + 2*DIM);
  s16x8 v1 = *(const s16x8*)(base + 2*DIM + 8);
  *(s16x8*)&vtile[tq*72 + j*16]     = v0;
  *(s16x8*)&vtile[tq*72 + j*16 + 8] = v1;
  __syncthreads();
  s16x8 o0, o1;
#pragma unroll
  for (int i = 0; i < 8; ++i){
    o0[i] = vtile[(j*16 + i)*72 + tq];
    o1[i] = vtile[(j*16 + 8 + i)*72 + tq];
  }
  short* vdst = vtb + ((size_t)bh*64 + tq)*Nc + tch*64 + j*16;
  *(s16x8*)vdst = o0; *(s16x8*)(vdst + 8) = o1;
}

// ============================================================
// Flash attention, 32x32 swapped form (working R2 version).
// ============================================================
__global__ __launch_bounds__(256) void attn_kern(const short* __restrict__ qln, const short* __restrict__ kln,
                                                 const short* __restrict__ vtb, short* __restrict__ attnv){
  __shared__ short Ks[64*72];
  __shared__ short Vs[64*72];
  int bh = blockIdx.x >> 4, qt = blockIdx.x & 15;
  int b = bh >> 4, h = bh & 15;
  int w = threadIdx.x >> 6, lane = threadIdx.x & 63;
  int lq = lane & 31, hi = lane >> 5;
  int qrow = qt*128 + w*32 + lq;

  const short* qp = qln + ((size_t)bh*Nc + qrow)*64 + hi*8;
  s16x8 qf[4];
#pragma unroll
  for (int m = 0; m < 4; ++m) qf[m] = *(const s16x8*)(qp + m*16);

  f32x16 o0 = {0,0,0,0,0,0,0,0,0,0,0,0,0,0,0,0};
  f32x16 o1 = {0,0,0,0,0,0,0,0,0,0,0,0,0,0,0,0};
  float mrun = -INFINITY, l = 0.f;

  int tr = threadIdx.x >> 2, seg = (threadIdx.x & 3) * 16;
  const short* kbase = kln + ((size_t)bh*Nc + tr)*64 + seg;
  const short* vbase = vtb + ((size_t)bh*64 + tr)*Nc + seg;
  short* ksd = &Ks[tr*72 + seg];
  short* vsd = &Vs[tr*72 + seg];

  for (int kt = 0; kt < Nc; kt += 64){
    const short* ksrc = kbase + (size_t)kt*64;
    *(s16x8*)ksd       = *(const s16x8*)ksrc;
    *(s16x8*)(ksd + 8) = *(const s16x8*)(ksrc + 8);
    const short* vsrc = vbase + kt;
    *(s16x8*)vsd       = *(const s16x8*)vsrc;
    *(s16x8*)(vsd + 8) = *(const s16x8*)(vsrc + 8);
    __syncthreads();

#pragma unroll
    for (int kc = 0; kc < 2; ++kc){
      f32x16 st = {0,0,0,0,0,0,0,0,0,0,0,0,0,0,0,0};
#pragma unroll
      for (int m = 0; m < 4; ++m){
        s16x8 kf = *(const s16x8*)&Ks[(kc*32 + lq)*72 + m*16 + hi*8];
        st = mfma3216(kf, qf[m], st);
      }
      float cmax = st[0];
#pragma unroll
      for (int r = 1; r < 16; ++r) cmax = fmaxf(cmax, st[r]);
      cmax = fmaxf(cmax, __shfl_xor(cmax, 32));
      if (__any(cmax > mrun + 8.f)){
        float mnew = fmaxf(mrun, cmax);
        float fr = EXP2F(mrun - mnew);
        l *= fr;
#pragma unroll
        for (int r = 0; r < 16; ++r){ o0[r] *= fr; o1[r] *= fr; }
        mrun = mnew;
      }
      float p[16];
#pragma unroll
      for (int r = 0; r < 16; ++r){ p[r] = EXP2F(st[r] - mrun); l += p[r]; }

#pragma unroll
      for (int kh = 0; kh < 2; ++kh){
        int r0 = kh*8;
        unsigned wa = pkbf(p[r0+0], p[r0+1]);
        unsigned wb = pkbf(p[r0+4], p[r0+5]);
        unsigned wc2 = pkbf(p[r0+2], p[r0+3]);
        unsigned wd = pkbf(p[r0+6], p[r0+7]);
        uint2v s1 = pl32swap(wa, wb);
        uint2v s2 = pl32swap(wc2, wd);
        union { unsigned u[4]; s16x8 v; } pu;
        pu.u[0] = s1[0]; pu.u[1] = s2[0]; pu.u[2] = s1[1]; pu.u[3] = s2[1];
        s16x8 vf0 = *(const s16x8*)&Vs[ lq      *72 + kc*32 + kh*16 + hi*8];
        s16x8 vf1 = *(const s16x8*)&Vs[(32 + lq)*72 + kc*32 + kh*16 + hi*8];
        o0 = mfma3216(vf0, pu.v, o0);
        o1 = mfma3216(vf1, pu.v, o1);
      }
    }
    __syncthreads();
  }

  l += __shfl_xor(l, 32);
  float inv = 1.f / l;
  short* orow = attnv + ((size_t)(b*Nc + qrow))*DIM + h*64;
#pragma unroll
  for (int r = 0; r < 16; r += 2){
    int dv = (r&3) + 8*(r>>2) + 4*hi;
    *(unsigned*)&orow[dv]      = pkbf(o0[r]*inv, o0[r+1]*inv);
    *(unsigned*)&orow[32 + dv] = pkbf(o1[r]*inv, o1[r+1]*inv);
  }
}

// ============================================================
// out = LayerNorm(a2 + p2) over 1024, fp32 out
// ============================================================
__global__ __launch_bounds__(256) void final_ln(const short* __restrict__ a2, const short* __restrict__ p2,
                                                float* __restrict__ out){
  __shared__ float red[16];
  int row = blockIdx.x, tid = threadIdx.x;
  size_t base = (size_t)row*DIM + tid*4;
  s16x4 a = *(const s16x4*)(a2 + base);
  s16x4 p = *(const s16x4*)(p2 + base);
  float v[4]; float s = 0.f, sq = 0.f;
#pragma unroll
  for (int i = 0; i < 4; ++i){ v[i] = b2f(a[i]) + b2f(p[i]); s += v[i]; sq += v[i]*v[i]; }
#pragma unroll
  for (int m = 1; m < 64; m <<= 1){ s += __shfl_xor(s, m); sq += __shfl_xor(sq, m); }
  int wv = tid >> 6;
  if ((tid & 63) == 0){ red[wv] = s; red[8 + wv] = sq; }
  __syncthreads();
  if (tid == 0){
    float S = red[0] + red[1] + red[2] + red[3];
    float Q = red[8] + red[9] + red[10] + red[11];
    float mu = S * (1.f/1024.f);
    float var = Q * (1.f/1024.f) - mu*mu;
    red[12] = mu; red[13] = rsqrtf(var + 1e-5f);
  }
  __syncthreads();
  float mu = red[12], inv = red[13];
#pragma unroll
  for (int i = 0; i < 4; ++i) out[base + i] = (v[i] - mu) * inv;
}

// ============================================================
extern "C" void kernel_launch(void* const* d_in, const int* in_sizes, int n_in,
                              void* d_out, int out_size, void* d_ws, size_t ws_size,
                              hipStream_t stream){
  const float* x    = (const float*)d_in[0];
  const float* Wqkv = (const float*)d_in[1];
  const float* W1   = (const float*)d_in[2];
  const float* b1   = (const float*)d_in[3];
  const float* W2   = (const float*)d_in[4];
  const float* b2   = (const float*)d_in[5];
  const float* Wout = (const float*)d_in[6];
  const float* bout = (const float*)d_in[7];
  float* out = (float*)d_out;
  char* ws = (char*)d_ws;

  short* xb    = (short*)(ws + OFF_XB);
  short* wqkvt = (short*)(ws + OFF_WQKVT);
  short* w1t   = (short*)(ws + OFF_W1T);
  short* w2t   = (short*)(ws + OFF_W2T);
  short* woutt = (short*)(ws + OFF_WOUTT);
  short* qkv   = (short*)(ws + OFF_QKV);
  short* qln   = (short*)(ws + OFF_QLN);
  short* kln   = (short*)(ws + OFF_KLN);
  short* vtb   = (short*)(ws + OFF_VT);
  short* attnv = (short*)(ws + OFF_ATTNV);
  short* hbuf  = (short*)(ws + OFF_H);
  short* p2    = (short*)(ws + OFF_P2);
  short* a2    = (short*)(ws + OFF_A2);

  conv_x<<<4096, 256, 0, stream>>>(x, xb);
  transpose_conv<<<(DIM/32)*(D3/32),  256, 0, stream>>>(Wqkv, wqkvt, DIM, D3);
  transpose_conv<<<(DIM/32)*(MLP/32), 256, 0, stream>>>(W1, w1t, DIM, MLP);
  transpose_conv<<<(MLP/32)*(DIM/32), 256, 0, stream>>>(W2, w2t, MLP, DIM);
  transpose_conv<<<(DIM/32)*(DIM/32), 256, 0, stream>>>(Wout, woutt, DIM, DIM);

  // qkv: BM=128 -> 768 blocks = exactly 3 rounds over 256 CUs (vs 384 = ragged 1.5)
  gemm8p<128,0><<<(Tc/128)*(D3/256), 512, 0, stream>>>(xb, wqkvt, qkv, nullptr, Tc, D3, DIM);
  ln_reorg<<<64*32, 256, 0, stream>>>(qkv, qln, kln, vtb);
  attn_kern<<<64*16, 256, 0, stream>>>(qln, kln, vtb, attnv);

  gemm8p<256,1><<<(Tc/256)*(MLP/256), 512, 0, stream>>>(xb, w1t, hbuf, b1, Tc, MLP, DIM);
  gemm8p<128,0><<<(Tc/128)*(DIM/256), 512, 0, stream>>>(hbuf, w2t, p2, b2, Tc, DIM, MLP);
  gemm8p<128,0><<<(Tc/128)*(DIM/256), 512, 0, stream>>>(attnv, woutt, a2, bout, Tc, DIM, DIM);

  final_ln<<<Tc, 256, 0, stream>>>(a2, p2, out);
}

// Round 5
// 419.585 us; speedup vs baseline: 1.2068x; 1.0511x over previous
//
#include <hip/hip_runtime.h>

typedef __attribute__((ext_vector_type(8))) short s16x8;
typedef __attribute__((ext_vector_type(4))) short s16x4;
typedef __attribute__((ext_vector_type(4))) float f32x4;
typedef __attribute__((ext_vector_type(16))) float f32x16;
typedef __attribute__((ext_vector_type(2))) unsigned uint2v;

#define DEVINL __device__ __forceinline__

// ---------- bf16 helpers ----------
DEVINL float b2f(short u){ return __uint_as_float(((unsigned)(unsigned short)u) << 16); }
DEVINL short f2bf(float f){
  unsigned u = __float_as_uint(f);
  u += 0x7fffu + ((u >> 16) & 1u);
  return (short)(u >> 16);
}
DEVINL unsigned pkbf(float a, float b){
  return (unsigned)(unsigned short)f2bf(a) | ((unsigned)(unsigned short)f2bf(b) << 16);
}
// HW packed f32->bf16 (RNE), one instr for two converts [T12 recipe]
DEVINL unsigned cvtpk(float lo, float hi){
  unsigned r;
  asm("v_cvt_pk_bf16_f32 %0, %1, %2" : "=v"(r) : "v"(lo), "v"(hi));
  return r;
}
DEVINL float max3f(float a, float b, float c){
  float r; asm("v_max3_f32 %0, %1, %2, %3" : "=v"(r) : "v"(a), "v"(b), "v"(c)); return r;
}

#if __has_builtin(__builtin_amdgcn_exp2f)
#define EXP2F __builtin_amdgcn_exp2f
#else
#define EXP2F exp2f
#endif

// ---------- MFMA wrappers ----------
DEVINL f32x4 mfma32(s16x8 a, s16x8 b, f32x4 c){
  return __builtin_amdgcn_mfma_f32_16x16x32_bf16(a, b, c, 0, 0, 0);
}
DEVINL f32x16 mfma3216(s16x8 a, s16x8 b, f32x16 c){
  // D: col=lane&31, row=(reg&3)+8*(reg>>2)+4*(lane>>5)  [verified R2]
  return __builtin_amdgcn_mfma_f32_32x32x16_bf16(a, b, c, 0, 0, 0);
}

DEVINL uint2v pl32swap(unsigned a, unsigned b){
#if __has_builtin(__builtin_amdgcn_permlane32_swap)
  return __builtin_amdgcn_permlane32_swap(a, b, false, false);
#else
  asm volatile("v_permlane32_swap_b32 %0, %1" : "+v"(a), "+v"(b));
  uint2v r; r[0] = a; r[1] = b; return r;
#endif
}

// ---------- async global->LDS (width 16) ----------
typedef const unsigned __attribute__((address_space(1)))* gas1;
typedef unsigned __attribute__((address_space(3)))* las3;
DEVINL void gload16(const short* g, short* l){
  __builtin_amdgcn_global_load_lds((gas1)g, (las3)l, 16, 0, 0);
}

// ---------- sync primitives ----------
#define CFENCE asm volatile("" ::: "memory")
#define PBAR  do{ CFENCE; __builtin_amdgcn_sched_barrier(0); __builtin_amdgcn_s_barrier(); \
                  __builtin_amdgcn_sched_barrier(0); CFENCE; }while(0)
#define VMW4 asm volatile("s_waitcnt vmcnt(4)" ::: "memory")
#define VMW3 asm volatile("s_waitcnt vmcnt(3)" ::: "memory")
#define VMW0 asm volatile("s_waitcnt vmcnt(0)" ::: "memory")

// ---------- problem constants ----------
static const int Bc   = 4;
static const int Nc   = 2048;
static const int DIM  = 1024;
static const int Tc   = Bc * Nc;      // 8192 tokens
static const int MLP  = 4096;
static const int D3   = 3072;

// ---------- ws layout (bytes) ----------
static const size_t OFF_XB    = 0;
static const size_t OFF_WQKVT = OFF_XB    + 16777216;
static const size_t OFF_W1T   = OFF_WQKVT + 6291456;
static const size_t OFF_W2T   = OFF_W1T   + 8388608;
static const size_t OFF_WOUTT = OFF_W2T   + 8388608;
static const size_t OFF_QKV   = OFF_WOUTT + 2097152;
static const size_t OFF_QLN   = OFF_QKV   + 50331648;
static const size_t OFF_KLN   = OFF_QLN   + 16777216;
static const size_t OFF_VT    = OFF_KLN   + 16777216;
static const size_t OFF_ATTNV = OFF_VT    + 16777216;
static const size_t OFF_H     = OFF_QKV;   // aliases of dead regions
static const size_t OFF_P2    = OFF_KLN;
static const size_t OFF_A2    = OFF_VT;

// ============================================================
// x fp32 -> bf16
// ============================================================
__global__ __launch_bounds__(256) void conv_x(const float* __restrict__ x, short* __restrict__ xb){
  size_t i = ((size_t)blockIdx.x * 256 + threadIdx.x) * 8;
  f32x4 v0 = *(const f32x4*)(x + i);
  f32x4 v1 = *(const f32x4*)(x + i + 4);
  s16x8 o;
#pragma unroll
  for (int j = 0; j < 4; ++j){ o[j] = f2bf(v0[j]); o[4+j] = f2bf(v1[j]); }
  *(s16x8*)(xb + i) = o;
}

// ============================================================
// W[K][N] fp32 -> Wt[N][K] bf16
// ============================================================
__global__ __launch_bounds__(256) void transpose_conv(const float* __restrict__ W, short* __restrict__ Wt,
                                                      int K, int N){
  __shared__ float tile[32][33];
  int ntx = N >> 5;
  int tx = blockIdx.x % ntx, ty = blockIdx.x / ntx;
  int r = threadIdx.x >> 3, c = (threadIdx.x & 7) * 4;
  f32x4 v = *(const f32x4*)(W + (size_t)(ty*32 + r)*N + tx*32 + c);
  tile[r][c] = v[0]; tile[r][c+1] = v[1]; tile[r][c+2] = v[2]; tile[r][c+3] = v[3];
  __syncthreads();
  s16x4 o;
#pragma unroll
  for (int j = 0; j < 4; ++j) o[j] = f2bf(tile[c+j][r]);
  *(s16x4*)(Wt + (size_t)(tx*32 + r)*K + ty*32 + c) = o;
}

// ============================================================
// Deep-pipelined GEMM (T1+T3+T4+T5) with k-group LDS swizzle.
// R5: BM=256 path reuses B-frags across the (k,m0)/(k,m1) phase pair.
// ============================================================
template<int BM, int ACT>
__global__ __launch_bounds__(512, 2) void gemm8p(const short* __restrict__ A, const short* __restrict__ Bt,
                                                 short* __restrict__ C, const float* __restrict__ bias,
                                                 int M, int N, int K){
  constexpr int MREP = BM/32;
  constexpr int ATOT = (BM==256) ? 32768 : 16384;  // shorts
  __shared__ short lds[ATOT + 32768];
  short* Ab = lds;
  short* Bb = lds + ATOT;

  const int tid = threadIdx.x;
  const int w = tid >> 6, lane = tid & 63;
  const int lr = lane & 15, g = lane >> 4;
  const int wr = w >> 2, wc = w & 3;              // 2 x 4 waves
  const int NT = K >> 6;

  const int nbn = N >> 8;
  const int cpx = gridDim.x >> 3;
  const int bid = (int)blockIdx.x;
  const int sw = (bid & 7)*cpx + (bid >> 3);      // XCD-chunked bijective swizzle
  const int bm = sw / nbn, bn = sw % nbn;

  const int l2 = lane >> 2;
  const int gsw = ((lane & 3) - ((lane >> 3) & 3)) & 3;
  const int cof = gsw * 8;
  const int qsw8 = (((g + (lr >> 1)) & 3)) * 8;

  const size_t arow = (BM==256) ? (size_t)(bm*256 + (w>>2)*128 + (w&3)*16 + l2)
                                : (size_t)(bm*128 + w*16 + l2);
  const short* ap0 = A  + arow*K + cof;
  const short* bp0 = Bt + (size_t)(bn*256 + w*16 + l2)*K + cof;

  auto stA = [&](int T, int kk, int mh){
    if constexpr (BM==256)
      gload16(ap0 + (size_t)mh*64*K + T*64 + kk*32, Ab + (((T&1)*2+kk)*2+mh)*4096 + w*512);
    else
      gload16(ap0 + T*64 + kk*32, Ab + ((T&1)*2+kk)*4096 + w*512);
  };
  auto stB = [&](int T, int kk, int j){
    gload16(bp0 + (size_t)j*128*K + T*64 + kk*32, Bb + ((T&1)*2+kk)*8192 + j*4096 + w*512);
  };
  auto ldA = [&](int buf, int kk, int mh, int mi)->s16x8{
    const int off = (BM==256) ? (((buf*2+kk)*2+mh)*4096) : ((buf*2+kk)*4096);
    return *(const s16x8*)&Ab[off + (wr*64 + mi*16 + lr)*32 + qsw8];
  };
  auto ldB = [&](int buf, int kk, int ni)->s16x8{
    return *(const s16x8*)&Bb[(buf*2+kk)*8192 + (wc*64 + ni*16 + lr)*32 + qsw8];
  };

  f32x4 acc[MREP][4] = {};

#define MMROW(ai, r) \
  acc[r][0]=mfma32(ai,b0,acc[r][0]); acc[r][1]=mfma32(ai,b1,acc[r][1]); \
  acc[r][2]=mfma32(ai,b2,acc[r][2]); acc[r][3]=mfma32(ai,b3,acc[r][3]);

  // ---- prologue ----
  if constexpr (BM==256){
    stA(0,0,0); stA(0,0,1); stB(0,0,0); stB(0,0,1);
    stA(0,1,0); stA(0,1,1); stB(0,1,0); stB(0,1,1);
    stA(1,0,0); stA(1,0,1); stB(1,0,0); stB(1,0,1);
    VMW4;
  } else {
    stA(0,0,0); stB(0,0,0); stB(0,0,1);
    stA(0,1,0); stB(0,1,0); stB(0,1,1);
    stA(1,0,0); stB(1,0,0); stB(1,0,1);
    VMW3;
  }
  PBAR;

  for (int t = 0; t < NT; ++t){
    const int buf = t & 1;
    const bool s1 = (t+1 < NT), s2 = (t+2 < NT);

    if constexpr (BM==256){
      s16x8 a0,a1,a2,a3,b0,b1,b2,b3;
      { // phase 1: (k0,m0), load B(k0) once ; stage t+1 A(k1,*)
        a0=ldA(buf,0,0,0); a1=ldA(buf,0,0,1); a2=ldA(buf,0,0,2); a3=ldA(buf,0,0,3);
        b0=ldB(buf,0,0); b1=ldB(buf,0,1); b2=ldB(buf,0,2); b3=ldB(buf,0,3);
        if (s1){ stA(t+1,1,0); stA(t+1,1,1); }
        PBAR;
        __builtin_amdgcn_s_setprio(1);
        MMROW(a0,0) MMROW(a1,1) MMROW(a2,2) MMROW(a3,3)
        __builtin_amdgcn_s_setprio(0);
        PBAR;
      }
      { // phase 2: (k0,m1), reuse b regs ; stage t+1 B(k1)
        a0=ldA(buf,0,1,0); a1=ldA(buf,0,1,1); a2=ldA(buf,0,1,2); a3=ldA(buf,0,1,3);
        if (s1){ stB(t+1,1,0); stB(t+1,1,1); }
        PBAR;
        __builtin_amdgcn_s_setprio(1);
        MMROW(a0,4) MMROW(a1,5) MMROW(a2,6) MMROW(a3,7)
        __builtin_amdgcn_s_setprio(0);
        PBAR;
      }
      { // phase 3: (k1,m0), load B(k1) ; stage t+2 A(k0,*)
        a0=ldA(buf,1,0,0); a1=ldA(buf,1,0,1); a2=ldA(buf,1,0,2); a3=ldA(buf,1,0,3);
        b0=ldB(buf,1,0); b1=ldB(buf,1,1); b2=ldB(buf,1,2); b3=ldB(buf,1,3);
        if (s2){ stA(t+2,0,0); stA(t+2,0,1); }
        PBAR;
        __builtin_amdgcn_s_setprio(1);
        MMROW(a0,0) MMROW(a1,1) MMROW(a2,2) MMROW(a3,3)
        __builtin_amdgcn_s_setprio(0);
        PBAR;
      }
      { // phase 4: (k1,m1), reuse b ; stage t+2 B(k0) ; counted vmcnt
        a0=ldA(buf,1,1,0); a1=ldA(buf,1,1,1); a2=ldA(buf,1,1,2); a3=ldA(buf,1,1,3);
        if (s2){ stB(t+2,0,0); stB(t+2,0,1); }
        PBAR;
        __builtin_amdgcn_s_setprio(1);
        MMROW(a0,4) MMROW(a1,5) MMROW(a2,6) MMROW(a3,7)
        __builtin_amdgcn_s_setprio(0);
        if (s2){ VMW4; } else { VMW0; }
        PBAR;
      }
    } else {
      { // phase 1: kk=0 ; stage t+1 {A(k1),B(k1)}
        s16x8 a0=ldA(buf,0,0,0), a1=ldA(buf,0,0,1), a2=ldA(buf,0,0,2), a3=ldA(buf,0,0,3);
        s16x8 b0=ldB(buf,0,0), b1=ldB(buf,0,1), b2=ldB(buf,0,2), b3=ldB(buf,0,3);
        if (s1){ stA(t+1,1,0); stB(t+1,1,0); stB(t+1,1,1); }
        PBAR;
        __builtin_amdgcn_s_setprio(1);
        MMROW(a0,0) MMROW(a1,1) MMROW(a2,2) MMROW(a3,3)
        __builtin_amdgcn_s_setprio(0);
        PBAR;
      }
      { // phase 2: kk=1 ; stage t+2 {A(k0),B(k0)}
        s16x8 a0=ldA(buf,1,0,0), a1=ldA(buf,1,0,1), a2=ldA(buf,1,0,2), a3=ldA(buf,1,0,3);
        s16x8 b0=ldB(buf,1,0), b1=ldB(buf,1,1), b2=ldB(buf,1,2), b3=ldB(buf,1,3);
        if (s2){ stA(t+2,0,0); stB(t+2,0,0); stB(t+2,0,1); }
        PBAR;
        __builtin_amdgcn_s_setprio(1);
        MMROW(a0,0) MMROW(a1,1) MMROW(a2,2) MMROW(a3,3)
        __builtin_amdgcn_s_setprio(0);
        if (s2){ VMW3; } else { VMW0; }
        PBAR;
      }
    }
  }
#undef MMROW

  // ---- epilogue ----
#pragma unroll
  for (int ni = 0; ni < 4; ++ni){
    const int col = bn*256 + wc*64 + ni*16 + lr;
    const float bv = bias ? bias[col] : 0.f;
#pragma unroll
    for (int a = 0; a < MREP; ++a){
      const int row0 = bm*BM + wr*(BM/2) + a*16 + 4*g;
      f32x4 v = acc[a][ni];
#pragma unroll
      for (int i = 0; i < 4; ++i){
        float val = v[i] + bv;
        if constexpr (ACT) val = 0.5f*val*(1.f + erff(val*0.70710678118f));
        C[(size_t)(row0+i)*N + col] = f2bf(val);
      }
    }
  }
}

// ============================================================
// q/k LayerNorm (d=64) + head-reorg; v -> Vt [bh][d][n]
// ============================================================
__global__ __launch_bounds__(256) void ln_reorg(const short* __restrict__ qkv, short* __restrict__ qln,
                                                short* __restrict__ kln, short* __restrict__ vtb){
  __shared__ short vtile[64*72];
  int bh = blockIdx.x >> 5, tch = blockIdx.x & 31;
  int b = bh >> 4, h = bh & 15;
  int tq = threadIdx.x >> 2, j = threadIdx.x & 3;
  size_t row = (size_t)b*Nc + tch*64 + tq;
  const short* base = qkv + row*D3 + h*64 + j*16;
  size_t orow = ((size_t)bh*Nc + tch*64 + tq)*64 + j*16;

#pragma unroll
  for (int part = 0; part < 2; ++part){
    const short* src = base + part*DIM;
    s16x8 u0 = *(const s16x8*)src;
    s16x8 u1 = *(const s16x8*)(src + 8);
    float f[16]; float s = 0.f, sq = 0.f;
#pragma unroll
    for (int i = 0; i < 8; ++i){ f[i] = b2f(u0[i]); f[8+i] = b2f(u1[i]); }
#pragma unroll
    for (int i = 0; i < 16; ++i){ s += f[i]; sq += f[i]*f[i]; }
    s  += __shfl_xor(s, 1);  s  += __shfl_xor(s, 2);
    sq += __shfl_xor(sq, 1); sq += __shfl_xor(sq, 2);
    float mu = s * (1.f/64.f);
    float var = sq * (1.f/64.f) - mu*mu;
    float inv = rsqrtf(var + 1e-5f) * (part == 0 ? 0.04508422003f : 1.f);
    s16x8 o0, o1;
#pragma unroll
    for (int i = 0; i < 8; ++i){ o0[i] = f2bf((f[i]-mu)*inv); o1[i] = f2bf((f[8+i]-mu)*inv); }
    short* dst = (part == 0 ? qln : kln) + orow;
    *(s16x8*)dst = o0; *(s16x8*)(dst + 8) = o1;
  }

  s16x8 v0 = *(const s16x8*)(base + 2*DIM);
  s16x8 v1 = *(const s16x8*)(base + 2*DIM + 8);
  *(s16x8*)&vtile[tq*72 + j*16]     = v0;
  *(s16x8*)&vtile[tq*72 + j*16 + 8] = v1;
  __syncthreads();
  s16x8 o0, o1;
#pragma unroll
  for (int i = 0; i < 8; ++i){
    o0[i] = vtile[(j*16 + i)*72 + tq];
    o1[i] = vtile[(j*16 + 8 + i)*72 + tq];
  }
  short* vdst = vtb + ((size_t)bh*64 + tq)*Nc + tch*64 + j*16;
  *(s16x8*)vdst = o0; *(s16x8*)(vdst + 8) = o1;
}

// ============================================================
// Flash attention, 32x32 swapped form.
// R5: KVBLK=128, T14 async-stage split (load next tile into regs under
// compute), cvt_pk bf16 packing, v_max3 reduction.
// ============================================================
__global__ __launch_bounds__(256) void attn_kern(const short* __restrict__ qln, const short* __restrict__ kln,
                                                 const short* __restrict__ vtb, short* __restrict__ attnv){
  __shared__ short Ks[128*72];    // [key][d64 +8 pad]
  __shared__ short Vs[64*136];    // [dv][key128 +8 pad]
  const int tid = threadIdx.x;
  const int bh = blockIdx.x >> 4, qt = blockIdx.x & 15;
  const int b = bh >> 4, h = bh & 15;
  const int w = tid >> 6, lane = tid & 63;
  const int lq = lane & 31, hi = lane >> 5;
  const int qrow = qt*128 + w*32 + lq;

  const short* qp = qln + ((size_t)bh*Nc + qrow)*64 + hi*8;
  s16x8 qf[4];
#pragma unroll
  for (int m = 0; m < 4; ++m) qf[m] = *(const s16x8*)(qp + m*16);

  f32x16 o0 = {0,0,0,0,0,0,0,0,0,0,0,0,0,0,0,0};
  f32x16 o1 = {0,0,0,0,0,0,0,0,0,0,0,0,0,0,0,0};
  float mrun = -INFINITY, l = 0.f;

  const short* kb0 = kln + (size_t)bh*Nc*64;
  const short* vb0 = vtb + (size_t)bh*64*Nc;
  const int vrow = tid >> 2, vq = tid & 3;

  // ---- prefetch tile 0 into regs ----
  s16x8 kr[4], vr[4];
#pragma unroll
  for (int j = 0; j < 4; ++j){
    kr[j] = *(const s16x8*)(kb0 + (size_t)(tid + j*256)*8);
    vr[j] = *(const s16x8*)(vb0 + (size_t)vrow*Nc + (vq + 4*j)*8);
  }

  for (int kt = 0; kt < 16; ++kt){
    // write prefetched tile to LDS
#pragma unroll
    for (int j = 0; j < 4; ++j){
      int s = tid + j*256;
      *(s16x8*)&Ks[(s>>3)*72 + (s&7)*8] = kr[j];
      *(s16x8*)&Vs[vrow*136 + (vq + 4*j)*8] = vr[j];
    }
    __syncthreads();
    // T14: issue next-tile loads; HBM latency hides under the 4 kc computes
    if (kt + 1 < 16){
      const short* kb = kb0 + (size_t)(kt+1)*128*64;
      const short* vb = vb0 + (kt+1)*128;
#pragma unroll
      for (int j = 0; j < 4; ++j){
        kr[j] = *(const s16x8*)(kb + (size_t)(tid + j*256)*8);
        vr[j] = *(const s16x8*)(vb + (size_t)vrow*Nc + (vq + 4*j)*8);
      }
    }

#pragma unroll
    for (int kc = 0; kc < 4; ++kc){
      f32x16 st = {0,0,0,0,0,0,0,0,0,0,0,0,0,0,0,0};
#pragma unroll
      for (int m = 0; m < 4; ++m){
        s16x8 kf = *(const s16x8*)&Ks[(kc*32 + lq)*72 + m*16 + hi*8];
        st = mfma3216(kf, qf[m], st);
      }
      float cmax = max3f(st[0], st[1], st[2]);
      cmax = max3f(cmax, st[3], st[4]);
      cmax = max3f(cmax, st[5], st[6]);
      cmax = max3f(cmax, st[7], st[8]);
      cmax = max3f(cmax, st[9], st[10]);
      cmax = max3f(cmax, st[11], st[12]);
      cmax = max3f(cmax, st[13], st[14]);
      cmax = fmaxf(cmax, st[15]);
      cmax = fmaxf(cmax, __shfl_xor(cmax, 32));
      if (__any(cmax > mrun + 8.f)){         // defer-max (T13)
        float mnew = fmaxf(mrun, cmax);
        float fr = EXP2F(mrun - mnew);
        l *= fr;
#pragma unroll
        for (int r = 0; r < 16; ++r){ o0[r] *= fr; o1[r] *= fr; }
        mrun = mnew;
      }
      float p[16];
#pragma unroll
      for (int r = 0; r < 16; ++r){ p[r] = EXP2F(st[r] - mrun); l += p[r]; }

#pragma unroll
      for (int kh = 0; kh < 2; ++kh){
        int r0 = kh*8;
        unsigned wa = cvtpk(p[r0+0], p[r0+1]);
        unsigned wb = cvtpk(p[r0+4], p[r0+5]);
        unsigned wc2 = cvtpk(p[r0+2], p[r0+3]);
        unsigned wd = cvtpk(p[r0+6], p[r0+7]);
        uint2v s1 = pl32swap(wa, wb);
        uint2v s2 = pl32swap(wc2, wd);
        union { unsigned u[4]; s16x8 v; } pu;
        pu.u[0] = s1[0]; pu.u[1] = s2[0]; pu.u[2] = s1[1]; pu.u[3] = s2[1];
        s16x8 vf0 = *(const s16x8*)&Vs[ lq      *136 + kc*32 + kh*16 + hi*8];
        s16x8 vf1 = *(const s16x8*)&Vs[(32 + lq)*136 + kc*32 + kh*16 + hi*8];
        o0 = mfma3216(vf0, pu.v, o0);
        o1 = mfma3216(vf1, pu.v, o1);
      }
    }
    __syncthreads();
  }

  l += __shfl_xor(l, 32);
  float inv = 1.f / l;
  short* orow = attnv + ((size_t)(b*Nc + qrow))*DIM + h*64;
#pragma unroll
  for (int r = 0; r < 16; r += 2){
    int dv = (r&3) + 8*(r>>2) + 4*hi;
    *(unsigned*)&orow[dv]      = cvtpk(o0[r]*inv, o0[r+1]*inv);
    *(unsigned*)&orow[32 + dv] = cvtpk(o1[r]*inv, o1[r+1]*inv);
  }
}

// ============================================================
// out = LayerNorm(a2 + p2) over 1024, fp32 out
// ============================================================
__global__ __launch_bounds__(256) void final_ln(const short* __restrict__ a2, const short* __restrict__ p2,
                                                float* __restrict__ out){
  __shared__ float red[16];
  int row = blockIdx.x, tid = threadIdx.x;
  size_t base = (size_t)row*DIM + tid*4;
  s16x4 a = *(const s16x4*)(a2 + base);
  s16x4 p = *(const s16x4*)(p2 + base);
  float v[4]; float s = 0.f, sq = 0.f;
#pragma unroll
  for (int i = 0; i < 4; ++i){ v[i] = b2f(a[i]) + b2f(p[i]); s += v[i]; sq += v[i]*v[i]; }
#pragma unroll
  for (int m = 1; m < 64; m <<= 1){ s += __shfl_xor(s, m); sq += __shfl_xor(sq, m); }
  int wv = tid >> 6;
  if ((tid & 63) == 0){ red[wv] = s; red[8 + wv] = sq; }
  __syncthreads();
  if (tid == 0){
    float S = red[0] + red[1] + red[2] + red[3];
    float Q = red[8] + red[9] + red[10] + red[11];
    float mu = S * (1.f/1024.f);
    float var = Q * (1.f/1024.f) - mu*mu;
    red[12] = mu; red[13] = rsqrtf(var + 1e-5f);
  }
  __syncthreads();
  float mu = red[12], inv = red[13];
#pragma unroll
  for (int i = 0; i < 4; ++i) out[base + i] = (v[i] - mu) * inv;
}

// ============================================================
extern "C" void kernel_launch(void* const* d_in, const int* in_sizes, int n_in,
                              void* d_out, int out_size, void* d_ws, size_t ws_size,
                              hipStream_t stream){
  const float* x    = (const float*)d_in[0];
  const float* Wqkv = (const float*)d_in[1];
  const float* W1   = (const float*)d_in[2];
  const float* b1   = (const float*)d_in[3];
  const float* W2   = (const float*)d_in[4];
  const float* b2   = (const float*)d_in[5];
  const float* Wout = (const float*)d_in[6];
  const float* bout = (const float*)d_in[7];
  float* out = (float*)d_out;
  char* ws = (char*)d_ws;

  short* xb    = (short*)(ws + OFF_XB);
  short* wqkvt = (short*)(ws + OFF_WQKVT);
  short* w1t   = (short*)(ws + OFF_W1T);
  short* w2t   = (short*)(ws + OFF_W2T);
  short* woutt = (short*)(ws + OFF_WOUTT);
  short* qkv   = (short*)(ws + OFF_QKV);
  short* qln   = (short*)(ws + OFF_QLN);
  short* kln   = (short*)(ws + OFF_KLN);
  short* vtb   = (short*)(ws + OFF_VT);
  short* attnv = (short*)(ws + OFF_ATTNV);
  short* hbuf  = (short*)(ws + OFF_H);
  short* p2    = (short*)(ws + OFF_P2);
  short* a2    = (short*)(ws + OFF_A2);

  conv_x<<<4096, 256, 0, stream>>>(x, xb);
  transpose_conv<<<(DIM/32)*(D3/32),  256, 0, stream>>>(Wqkv, wqkvt, DIM, D3);
  transpose_conv<<<(DIM/32)*(MLP/32), 256, 0, stream>>>(W1, w1t, DIM, MLP);
  transpose_conv<<<(MLP/32)*(DIM/32), 256, 0, stream>>>(W2, w2t, MLP, DIM);
  transpose_conv<<<(DIM/32)*(DIM/32), 256, 0, stream>>>(Wout, woutt, DIM, DIM);

  gemm8p<128,0><<<(Tc/128)*(D3/256), 512, 0, stream>>>(xb, wqkvt, qkv, nullptr, Tc, D3, DIM);
  ln_reorg<<<64*32, 256, 0, stream>>>(qkv, qln, kln, vtb);
  attn_kern<<<64*16, 256, 0, stream>>>(qln, kln, vtb, attnv);

  gemm8p<256,1><<<(Tc/256)*(MLP/256), 512, 0, stream>>>(xb, w1t, hbuf, b1, Tc, MLP, DIM);
  gemm8p<128,0><<<(Tc/128)*(DIM/256), 512, 0, stream>>>(hbuf, w2t, p2, b2, Tc, DIM, MLP);
  gemm8p<128,0><<<(Tc/128)*(DIM/256), 512, 0, stream>>>(attnv, woutt, a2, bout, Tc, DIM, DIM);

  final_ln<<<Tc, 256, 0, stream>>>(a2, p2, out);
}